// Round 7
// baseline (5464.069 us; speedup 1.0000x reference)
//
#include <hip/hip_runtime.h>
#include <cstdint>
#include <cstddef>

#define NN 500
#define KP 512   // node dim padded to 512 for f16 MFMA operands

typedef _Float16 f16;
typedef _Float16 half8 __attribute__((ext_vector_type(8)));
typedef float floatx4 __attribute__((ext_vector_type(4)));

// 6 A-sharing groups; each: acc += A*B1^T (+ A*B2^T). 10 MFMA passes, 6 A reads.
struct MSet {
  const f16* A[6];
  const f16* B1[6];
  const f16* B2[6];   // nullptr -> single-B group
};

// ---------------------------------------------------------------------------
// adp = softmax(relu(E1 @ E2), axis=1)
__global__ __launch_bounds__(256) void adp_kernel(const float* __restrict__ e1,
                                                  const float* __restrict__ e2,
                                                  float* __restrict__ adp) {
  int r = blockIdx.x;
  int tid = threadIdx.x;
  __shared__ float red[256];
  __shared__ float e1row[16];
  if (tid < 10) e1row[tid] = e1[r * 10 + tid];
  __syncthreads();
  float z0, z1 = 0.f;
  {
    float acc = 0.f;
#pragma unroll
    for (int k = 0; k < 10; k++) acc += e1row[k] * e2[k * NN + tid];
    z0 = fmaxf(acc, 0.f);
  }
  bool has1 = (tid + 256) < NN;
  if (has1) {
    float acc = 0.f;
#pragma unroll
    for (int k = 0; k < 10; k++) acc += e1row[k] * e2[k * NN + tid + 256];
    z1 = fmaxf(acc, 0.f);
  }
  float mx = has1 ? fmaxf(z0, z1) : z0;
  red[tid] = mx;
  __syncthreads();
  for (int s = 128; s > 0; s >>= 1) {
    if (tid < s) red[tid] = fmaxf(red[tid], red[tid + s]);
    __syncthreads();
  }
  mx = red[0];
  __syncthreads();
  float ex0 = __expf(z0 - mx);
  float ex1 = has1 ? __expf(z1 - mx) : 0.f;
  red[tid] = ex0 + ex1;
  __syncthreads();
  for (int s = 128; s > 0; s >>= 1) {
    if (tid < s) red[tid] += red[tid + s];
    __syncthreads();
  }
  float inv = 1.f / red[0];
  adp[r * NN + tid] = ex0 * inv;
  if (has1) adp[r * NN + tid + 256] = ex1 * inv;
}

// ---------------------------------------------------------------------------
// xT[bc][t][n] = x[bc][n][t]  (coalesced reads for the fused layer-0 dconv)
__global__ __launch_bounds__(256) void xt_kernel(const float* __restrict__ x,
                                                 float* __restrict__ xT) {
  __shared__ float tile[32][33];
  int tx = threadIdx.x & 31, ty = threadIdx.x >> 5;
  int n0 = blockIdx.x * 32, t0 = blockIdx.y * 32, bc = blockIdx.z;
#pragma unroll
  for (int rr = 0; rr < 4; rr++) {
    int n = n0 + ty + rr * 8, t = t0 + tx;
    tile[ty + rr * 8][tx] = (n < NN) ? x[((size_t)bc * NN + n) * 256 + t] : 0.f;
  }
  __syncthreads();
#pragma unroll
  for (int rr = 0; rr < 4; rr++) {
    int t = t0 + ty + rr * 8, n = n0 + tx;
    if (n < NN) xT[((size_t)bc * 256 + t) * NN + n] = tile[tx][ty + rr * 8];
  }
}

// ---------------------------------------------------------------------------
// B^T as f16 hi/lo pair: hi[w][v]+lo[w][v] ~= src[v][w], 512x512 zero-padded.
__global__ __launch_bounds__(256) void bt_kernel(const float* __restrict__ src,
                                                 f16* __restrict__ hi,
                                                 f16* __restrict__ lo) {
  int idx = blockIdx.x * 256 + threadIdx.x;  // 512*512 total
  int w = idx >> 9, v = idx & 511;
  float x = (w < NN && v < NN) ? src[v * NN + w] : 0.f;
  f16 h = (f16)x;
  hi[idx] = h;
  lo[idx] = (f16)(x - (float)h);
}

// ---------------------------------------------------------------------------
// Squared-matrix B^T pair: dst[w][v] = (src @ src)[v][w].
__global__ __launch_bounds__(512) void sq_kernel(const float* __restrict__ srcA,
                                                 const float* __restrict__ srcB,
                                                 f16* __restrict__ hiA, f16* __restrict__ loA,
                                                 f16* __restrict__ hiB, f16* __restrict__ loB) {
  const float* src = blockIdx.y == 0 ? srcA : srcB;
  f16* hi = blockIdx.y == 0 ? hiA : hiB;
  f16* lo = blockIdx.y == 0 ? loA : loB;
  int v = blockIdx.x;   // 0..511
  int w = threadIdx.x;  // 0..511
  __shared__ float vrow[512];
  vrow[w] = (v < NN && w < NN) ? src[v * NN + w] : 0.f;
  __syncthreads();
  float acc = 0.f;
  if (v < NN && w < NN) {
#pragma unroll 4
    for (int u = 0; u < NN; u++) acc = fmaf(vrow[u], src[u * NN + w], acc);
  }
  size_t o = (size_t)w * 512 + v;
  f16 h = (f16)acc;
  hi[o] = h;
  lo[o] = (f16)(acc - (float)h);
}

// ---------------------------------------------------------------------------
// Zero pad columns [500,512) of the six f16 P arrays (ws re-poisoned 0xAA).
__global__ __launch_bounds__(256) void padzero_kernel(uint32_t* __restrict__ slab, int R) {
  int idx = blockIdx.x * 256 + threadIdx.x;
  int total = 6 * R * 6;
  if (idx >= total) return;
  int a = idx / (R * 6);
  int rem = idx - a * R * 6;
  int row = rem / 6;
  int q = rem - row * 6;
  slab[(size_t)a * R * 256 + (size_t)row * 256 + 250 + q] = 0u;
}

// ---------------------------------------------------------------------------
// Fused (start-conv) + dilated-conv + gating + GCN channel-mix. FG in registers.
// FUSED=true (layer 0): h comes from start-conv of xT on the fly (no h0 buffer).
// P1 terms single f16 (B-side row-norm ~13: err ~8e-4); P2 terms hi/lo pairs
// (they hit A^2, row-norm ~2800). All register-array index loops fully
// unrolled (scratch-demotion hazard, round-1).
template <bool FUSED>
__global__ __launch_bounds__(256) void dcm_kernel(
    const float* __restrict__ hprev, const float* __restrict__ xT,
    const float* __restrict__ sw, const float* __restrict__ sb,
    const float* __restrict__ fw, const float* __restrict__ fb,
    const float* __restrict__ gw, const float* __restrict__ gb,
    const float* __restrict__ cw, const float* __restrict__ cb,
    float* __restrict__ Hout,
    f16* __restrict__ P1a,
    f16* __restrict__ P2aH, f16* __restrict__ P2aL,
    f16* __restrict__ P1b,
    f16* __restrict__ P2bH, f16* __restrict__ P2bL,
    float* __restrict__ tapL,
    int Lp, int L, int b0) {
  int nc = blockIdx.x, j = blockIdx.y, bb = blockIdx.z;
  int n = nc * 256 + threadIdx.x;
  if (n >= NN) return;
  size_t base = ((size_t)(bb * 32) * Lp + 2 * j) * NN + n;
  size_t cs = (size_t)Lp * NN;
  float x00 = 0.f, x01 = 0.f, x10 = 0.f, x11 = 0.f;
  if (FUSED) {
    const float* xb = xT + (size_t)(b0 + bb) * 2 * 256 * NN;
    x00 = xb[(size_t)(2 * j) * NN + n];
    x01 = xb[(size_t)(2 * j + 1) * NN + n];
    x10 = xb[(size_t)(256 + 2 * j) * NN + n];
    x11 = xb[(size_t)(256 + 2 * j + 1) * NN + n];
  }
  float FG[32];
#pragma unroll
  for (int half = 0; half < 2; half++) {
    float accf[16], accg[16];
#pragma unroll
    for (int c = 0; c < 16; c++) {
      accf[c] = fb[half * 16 + c];
      accg[c] = gb[half * 16 + c];
    }
    for (int cp = 0; cp < 32; cp++) {
      float v0, v1;
      if (FUSED) {
        float w0 = sw[cp * 2], w1 = sw[cp * 2 + 1], bc = sb[cp];
        v0 = fmaf(w0, x00, fmaf(w1, x10, bc));
        v1 = fmaf(w0, x01, fmaf(w1, x11, bc));
      } else {
        v0 = hprev[base + cp * cs];
        v1 = hprev[base + cp * cs + NN];
      }
      const float* fwp = fw + (half * 16) * 64 + cp * 2;  // [c][cp][tap]
      const float* gwp = gw + (half * 16) * 64 + cp * 2;
#pragma unroll
      for (int c = 0; c < 16; c++) {
        accf[c] = fmaf(fwp[c * 64], v0, accf[c]);
        accf[c] = fmaf(fwp[c * 64 + 1], v1, accf[c]);
        accg[c] = fmaf(gwp[c * 64], v0, accg[c]);
        accg[c] = fmaf(gwp[c * 64 + 1], v1, accg[c]);
      }
    }
#pragma unroll
    for (int c = 0; c < 16; c++) {
      float E = __expf(2.f * accf[c]);
      float th = 1.f - 2.f / (E + 1.f);          // tanh
      float sg = 1.f / (1.f + __expf(-accg[c])); // sigmoid
      FG[half * 16 + c] = th * sg;
    }
  }
  if (j == L - 1) {
    size_t tbase = ((size_t)(b0 + bb) * 32) * NN + n;
#pragma unroll
    for (int c = 0; c < 32; c++) tapL[tbase + (size_t)c * NN] = FG[c];
  }
  if (Hout == nullptr) return;  // layer 8: only the skip tap survives
#pragma unroll 2
  for (int c = 0; c < 32; c++) {
    const float* wr = cw + c * 160;
    float h = cb[c], p1 = 0.f, p2 = 0.f, q1 = 0.f, q2 = 0.f;
#pragma unroll
    for (int cp = 0; cp < 32; cp++) {
      float f = FG[cp];
      h  = fmaf(wr[cp], f, h);
      p1 = fmaf(wr[32 + cp], f, p1);
      p2 = fmaf(wr[64 + cp], f, p2);
      q1 = fmaf(wr[96 + cp], f, q1);
      q2 = fmaf(wr[128 + cp], f, q2);
    }
    // residual = hprev[2j+1] (start-conv output for layer 0)
    if (FUSED) {
      h += fmaf(sw[c * 2], x01, fmaf(sw[c * 2 + 1], x11, sb[c]));
    } else {
      h += hprev[((size_t)(bb * 32 + c) * Lp + 2 * j + 1) * NN + n];
    }
    size_t mi = (size_t)(bb * 32 + c) * L + j;
    Hout[mi * NN + n] = h;
    size_t o = mi * KP + n;
    f16 t;
    P1a[o] = (f16)p1;
    t = (f16)p2; P2aH[o] = t; P2aL[o] = (f16)(p2 - (float)t);
    P1b[o] = (f16)q1;
    t = (f16)q2; P2bH[o] = t; P2bL[o] = (f16)(q2 - (float)t);
  }
}

// ---------------------------------------------------------------------------
// B-resident GCN node-mix GEMM: block = 32m x 512n (A rows read exactly ONCE;
// B slab ~3MB stays L2-resident). 4 waves, each 32m x 128n = 2x8 subtiles of
// mfma 16x16x32. j processed in halves of 4 to bound register live ranges
// (round-5 spill lesson). Out[m,w] = BN(Cin + sum_g A_g . (B1_g+B2_g)).
__global__ __launch_bounds__(256) void mfma_gcn(MSet s,
    const float* __restrict__ Cin, float* __restrict__ Out, int M,
    const float* __restrict__ bng, const float* __restrict__ bnb, int lshift) {
  int tid = threadIdx.x;
  int wave = tid >> 6, lane = tid & 63;
  int m0 = blockIdx.x * 32;
  int n0 = wave * 128;
  int lm = lane & 15, kq = lane >> 4;  // operand frag: row lm, k-quad kq (8 k)
  floatx4 acc[2][8];
#pragma unroll
  for (int i = 0; i < 2; i++)
#pragma unroll
    for (int j = 0; j < 8; j++) acc[i][j] = (floatx4){0.f, 0.f, 0.f, 0.f};
  size_t arow[2];
#pragma unroll
  for (int i = 0; i < 2; i++) arow[i] = (size_t)(m0 + i * 16 + lm) * KP + kq * 8;
  size_t brow[8];
#pragma unroll
  for (int j = 0; j < 8; j++) brow[j] = (size_t)(n0 + j * 16 + lm) * KP + kq * 8;

  for (int gi = 0; gi < 6; gi++) {
    const f16* __restrict__ Ap = s.A[gi];
    const f16* __restrict__ B1p = s.B1[gi];
    const f16* __restrict__ B2p = s.B2[gi];
    if (B2p != nullptr) {
      for (int k0 = 0; k0 < KP; k0 += 32) {
        half8 av[2];
#pragma unroll
        for (int i = 0; i < 2; i++) av[i] = *(const half8*)(Ap + arow[i] + k0);
#pragma unroll
        for (int h = 0; h < 2; h++) {
          half8 b1[4], b2[4];
#pragma unroll
          for (int jj = 0; jj < 4; jj++) b1[jj] = *(const half8*)(B1p + brow[h * 4 + jj] + k0);
#pragma unroll
          for (int jj = 0; jj < 4; jj++) b2[jj] = *(const half8*)(B2p + brow[h * 4 + jj] + k0);
#pragma unroll
          for (int jj = 0; jj < 4; jj++)
#pragma unroll
            for (int i = 0; i < 2; i++)
              acc[i][h * 4 + jj] = __builtin_amdgcn_mfma_f32_16x16x32_f16(av[i], b1[jj], acc[i][h * 4 + jj], 0, 0, 0);
#pragma unroll
          for (int jj = 0; jj < 4; jj++)
#pragma unroll
            for (int i = 0; i < 2; i++)
              acc[i][h * 4 + jj] = __builtin_amdgcn_mfma_f32_16x16x32_f16(av[i], b2[jj], acc[i][h * 4 + jj], 0, 0, 0);
        }
      }
    } else {
      for (int k0 = 0; k0 < KP; k0 += 32) {
        half8 av[2];
#pragma unroll
        for (int i = 0; i < 2; i++) av[i] = *(const half8*)(Ap + arow[i] + k0);
#pragma unroll
        for (int h = 0; h < 2; h++) {
          half8 b1[4];
#pragma unroll
          for (int jj = 0; jj < 4; jj++) b1[jj] = *(const half8*)(B1p + brow[h * 4 + jj] + k0);
#pragma unroll
          for (int jj = 0; jj < 4; jj++)
#pragma unroll
            for (int i = 0; i < 2; i++)
              acc[i][h * 4 + jj] = __builtin_amdgcn_mfma_f32_16x16x32_f16(av[i], b1[jj], acc[i][h * 4 + jj], 0, 0, 0);
        }
      }
    }
  }
  // epilogue: C/D layout col = lane&15, row = (lane>>4)*4 + reg
  int cn = lane & 15, rq = lane >> 4;
  float rs = rsqrtf(1.f + 1e-5f);
#pragma unroll
  for (int i = 0; i < 2; i++) {
#pragma unroll
    for (int r = 0; r < 4; r++) {
      int row = m0 + i * 16 + rq * 4 + r;
      if (row < M) {
        int c = (row >> lshift) & 31;  // m = (bb*32+c)*L + j
        float scale = bng[c] * rs;
        float bias = bnb[c];
#pragma unroll
        for (int j = 0; j < 8; j++) {
          int col = n0 + j * 16 + cn;
          if (col < NN) {
            size_t o = (size_t)row * NN + col;
            Out[o] = (acc[i][j][r] + Cin[o]) * scale + bias;
          }
        }
      }
    }
  }
}

// ---------------------------------------------------------------------------
// skip -> relu -> end1 -> relu -> end2. One block per (b, 20 n-values).
#define NB 20
#define NBP 21
__global__ __launch_bounds__(256) void final_kernel(const float* __restrict__ tap,
    const float* __restrict__ skw, const float* __restrict__ skb,
    const float* __restrict__ e1w, const float* __restrict__ e1b,
    const float* __restrict__ e2w, const float* __restrict__ e2b,
    float* __restrict__ out) {
  __shared__ float tapS[256][NBP];
  __shared__ float skS[256][NBP];
  __shared__ float e1S[512][NBP];
  int tid = threadIdx.x;
  int b = blockIdx.y;
  int n0 = blockIdx.x * NB;
  {
    int i = tid >> 5, c = tid & 31;
    const float* tp = tap + (((size_t)i * 8 + b) * 32 + c) * NN + n0;
#pragma unroll
    for (int v = 0; v < NB; v++) tapS[tid][v] = tp[v];
  }
  __syncthreads();
  {
    float bsum = 0.f;
#pragma unroll
    for (int i2 = 0; i2 < 8; i2++) bsum += skb[i2 * 256 + tid];
    float acc[NB];
#pragma unroll
    for (int v = 0; v < NB; v++) acc[v] = bsum;
#pragma unroll
    for (int i2 = 0; i2 < 8; i2++) {
      const float* wr = skw + ((size_t)i2 * 256 + tid) * 32;
#pragma unroll
      for (int cp = 0; cp < 32; cp++) {
        float w = wr[cp];
#pragma unroll
        for (int v = 0; v < NB; v++) acc[v] = fmaf(w, tapS[i2 * 32 + cp][v], acc[v]);
      }
    }
#pragma unroll
    for (int v = 0; v < NB; v++) skS[tid][v] = fmaxf(acc[v], 0.f);
  }
  __syncthreads();
#pragma unroll
  for (int h = 0; h < 2; h++) {
    int k = tid + h * 256;
    float bv = e1b[k];
    float acc[NB];
#pragma unroll
    for (int v = 0; v < NB; v++) acc[v] = bv;
    const float* wr = e1w + (size_t)k * 256;
    for (int o = 0; o < 256; o++) {
      float w = wr[o];
#pragma unroll
      for (int v = 0; v < NB; v++) acc[v] = fmaf(w, skS[o][v], acc[v]);
    }
#pragma unroll
    for (int v = 0; v < NB; v++) e1S[k][v] = fmaxf(acc[v], 0.f);
  }
  __syncthreads();
  if (tid < 12 * NB) {
    int q = tid / NB, v = tid % NB;
    float acc = e2b[q];
    const float* wr = e2w + (size_t)q * 512;
#pragma unroll 8
    for (int k = 0; k < 512; k++) acc = fmaf(wr[k], e1S[k][v], acc);
    out[((size_t)b * 12 + q) * NN + n0 + v] = acc;
  }
}

// ---------------------------------------------------------------------------
extern "C" void kernel_launch(void* const* d_in, const int* in_sizes, int n_in,
                              void* d_out, int out_size, void* d_ws, size_t ws_size,
                              hipStream_t stream) {
  const float* x       = (const float*)d_in[0];
  const float* A0      = (const float*)d_in[1];
  const float* start_w = (const float*)d_in[2];
  const float* start_b = (const float*)d_in[3];
  const float* filt_w  = (const float*)d_in[4];
  const float* filt_b  = (const float*)d_in[5];
  const float* gate_w  = (const float*)d_in[6];
  const float* gate_b  = (const float*)d_in[7];
  const float* skip_w  = (const float*)d_in[8];
  const float* skip_b  = (const float*)d_in[9];
  const float* gcn_w   = (const float*)d_in[10];
  const float* gcn_b   = (const float*)d_in[11];
  const float* bn_g    = (const float*)d_in[12];
  const float* bn_b    = (const float*)d_in[13];
  const float* nv1     = (const float*)d_in[14];
  const float* nv2     = (const float*)d_in[15];
  const float* e1w     = (const float*)d_in[16];
  const float* e1b     = (const float*)d_in[17];
  const float* e2w     = (const float*)d_in[18];
  const float* e2b     = (const float*)d_in[19];
  float* out = (float*)d_out;

  char* ws = (char*)d_ws;
  size_t off = 0;
  auto alloc = [&](size_t bytes) -> void* {
    void* p = (void*)(ws + off);
    off += (bytes + 255) & ~(size_t)255;
    return p;
  };
  float* adp   = (float*)alloc((size_t)NN * NN * 4);
  float* tap   = (float*)alloc((size_t)8 * 8 * 32 * NN * 4);
  float* xT    = (float*)alloc((size_t)16 * 256 * NN * 4);  // [b*2+ch][t][n]
  f16*   A0tH  = (f16*)alloc((size_t)KP * KP * 2);
  f16*   A0tL  = (f16*)alloc((size_t)KP * KP * 2);
  f16*   adptH = (f16*)alloc((size_t)KP * KP * 2);
  f16*   adptL = (f16*)alloc((size_t)KP * KP * 2);
  f16*   Q0H   = (f16*)alloc((size_t)KP * KP * 2);   // (A0^2)^T pair
  f16*   Q0L   = (f16*)alloc((size_t)KP * KP * 2);
  f16*   QdH   = (f16*)alloc((size_t)KP * KP * 2);   // (adp^2)^T pair
  f16*   QdL   = (f16*)alloc((size_t)KP * KP * 2);
  size_t fixed = off;
  // per-batch: h128 (L<=128) + h64 (L<=64) fp32 + 6 f16 arrays [32*128 x 512]
  const size_t perg = 8192000ull + 4096000ull + 6ull * 4194304ull;  // 37.45 MB
  int g = 8;
  while (g > 1 && fixed + (size_t)g * perg + 1048576 > ws_size) g >>= 1;
  float* h128 = (float*)alloc((size_t)g * 8192000ull);
  float* h64  = (float*)alloc((size_t)g * 4096000ull);
  f16* slab   = (f16*)alloc(6ull * g * 4194304ull);
  int R = g * 4096;  // rows per f16 array (layer-0 M)
  f16* P1a  = slab + 0ull * R * KP;
  f16* P2aH = slab + 1ull * R * KP;
  f16* P2aL = slab + 2ull * R * KP;
  f16* P1b  = slab + 3ull * R * KP;
  f16* P2bH = slab + 4ull * R * KP;
  f16* P2bL = slab + 5ull * R * KP;

  adp_kernel<<<NN, 256, 0, stream>>>(nv1, nv2, adp);
  xt_kernel<<<dim3(16, 8, 16), 256, 0, stream>>>(x, xT);
  bt_kernel<<<1024, 256, 0, stream>>>(A0, A0tH, A0tL);
  bt_kernel<<<1024, 256, 0, stream>>>(adp, adptH, adptL);
  sq_kernel<<<dim3(512, 2), 512, 0, stream>>>(A0, adp, Q0H, Q0L, QdH, QdL);
  padzero_kernel<<<(36 * R + 255) / 256, 256, 0, stream>>>((uint32_t*)slab, R);

  // out = H + P1a*A0 + P2a*A0^2 + P1b*adp + P2b*adp^2; P2 terms as hi/lo
  // pairs (3 passes, lo*lo dropped), P1 terms single-f16 (2 passes).
  MSet s{};
  s.A[0] = P1a;  s.B1[0] = A0tH;  s.B2[0] = A0tL;
  s.A[1] = P2aH; s.B1[1] = Q0H;   s.B2[1] = Q0L;
  s.A[2] = P2aL; s.B1[2] = Q0H;   s.B2[2] = nullptr;
  s.A[3] = P1b;  s.B1[3] = adptH; s.B2[3] = adptL;
  s.A[4] = P2bH; s.B1[4] = QdH;   s.B2[4] = QdL;
  s.A[5] = P2bL; s.B1[5] = QdH;   s.B2[5] = nullptr;

  for (int b0 = 0; b0 < 8; b0 += g) {
    float* hprev = nullptr;
    int Lp = 256;
    for (int i = 0; i < 8; i++) {
      int L = Lp >> 1;  // 128,64,...,1
      if (i < 7) {
        float* hout = (i & 1) ? h64 : h128;
        if (i == 0) {
          dcm_kernel<true><<<dim3(2, L, g), 256, 0, stream>>>(
              nullptr, xT, start_w, start_b,
              filt_w + i * 2048, filt_b + i * 32, gate_w + i * 2048, gate_b + i * 32,
              gcn_w + i * 5120, gcn_b + i * 32, hout,
              P1a, P2aH, P2aL, P1b, P2bH, P2bL,
              tap + (size_t)i * 8 * 32 * NN, Lp, L, b0);
        } else {
          dcm_kernel<false><<<dim3(2, L, g), 256, 0, stream>>>(
              hprev, nullptr, nullptr, nullptr,
              filt_w + i * 2048, filt_b + i * 32, gate_w + i * 2048, gate_b + i * 32,
              gcn_w + i * 5120, gcn_b + i * 32, hout,
              P1a, P2aH, P2aL, P1b, P2bH, P2bL,
              tap + (size_t)i * 8 * 32 * NN, Lp, L, b0);
        }
        int M = g * 32 * L;
        mfma_gcn<<<dim3(M / 32), 256, 0, stream>>>(s, hout, hout, M,
                                                   bn_g + i * 32, bn_b + i * 32, 7 - i);
        hprev = hout;
        Lp = L;
      } else {
        // layer 8: only the skip tap survives
        dcm_kernel<false><<<dim3(2, 1, g), 256, 0, stream>>>(
            hprev, nullptr, nullptr, nullptr,
            filt_w + i * 2048, filt_b + i * 32, gate_w + i * 2048, gate_b + i * 32,
            gcn_w, gcn_b, nullptr,
            P1a, P2aH, P2aL, P1b, P2bH, P2bL,
            tap + (size_t)i * 8 * 32 * NN, Lp, 1, b0);
      }
    }
  }
  final_kernel<<<dim3(25, 8), 256, 0, stream>>>(tap, skip_w, skip_b, e1w, e1b, e2w, e2b, out);
}

// Round 9
// 4555.231 us; speedup vs baseline: 1.1995x; 1.1995x over previous
//
#include <hip/hip_runtime.h>
#include <cstdint>
#include <cstddef>

#define NN 500
#define KP 512   // node dim padded to 512 for f16 MFMA operands

typedef _Float16 f16;
typedef _Float16 half8 __attribute__((ext_vector_type(8)));
typedef float floatx4 __attribute__((ext_vector_type(4)));

// 6 A-sharing groups; each: acc += A*B1^T (+ A*B2^T). 10 MFMA passes, 6 A reads.
struct MSet {
  const f16* A[6];
  const f16* B1[6];
  const f16* B2[6];   // nullptr -> single-B group
};

// ---------------------------------------------------------------------------
// adp = softmax(relu(E1 @ E2), axis=1)
__global__ __launch_bounds__(256) void adp_kernel(const float* __restrict__ e1,
                                                  const float* __restrict__ e2,
                                                  float* __restrict__ adp) {
  int r = blockIdx.x;
  int tid = threadIdx.x;
  __shared__ float red[256];
  __shared__ float e1row[16];
  if (tid < 10) e1row[tid] = e1[r * 10 + tid];
  __syncthreads();
  float z0, z1 = 0.f;
  {
    float acc = 0.f;
#pragma unroll
    for (int k = 0; k < 10; k++) acc += e1row[k] * e2[k * NN + tid];
    z0 = fmaxf(acc, 0.f);
  }
  bool has1 = (tid + 256) < NN;
  if (has1) {
    float acc = 0.f;
#pragma unroll
    for (int k = 0; k < 10; k++) acc += e1row[k] * e2[k * NN + tid + 256];
    z1 = fmaxf(acc, 0.f);
  }
  float mx = has1 ? fmaxf(z0, z1) : z0;
  red[tid] = mx;
  __syncthreads();
  for (int s = 128; s > 0; s >>= 1) {
    if (tid < s) red[tid] = fmaxf(red[tid], red[tid + s]);
    __syncthreads();
  }
  mx = red[0];
  __syncthreads();
  float ex0 = __expf(z0 - mx);
  float ex1 = has1 ? __expf(z1 - mx) : 0.f;
  red[tid] = ex0 + ex1;
  __syncthreads();
  for (int s = 128; s > 0; s >>= 1) {
    if (tid < s) red[tid] += red[tid + s];
    __syncthreads();
  }
  float inv = 1.f / red[0];
  adp[r * NN + tid] = ex0 * inv;
  if (has1) adp[r * NN + tid + 256] = ex1 * inv;
}

// ---------------------------------------------------------------------------
// xT[bc][t][n] = x[bc][n][t]  (coalesced reads for the fused layer-0 dconv)
__global__ __launch_bounds__(256) void xt_kernel(const float* __restrict__ x,
                                                 float* __restrict__ xT) {
  __shared__ float tile[32][33];
  int tx = threadIdx.x & 31, ty = threadIdx.x >> 5;
  int n0 = blockIdx.x * 32, t0 = blockIdx.y * 32, bc = blockIdx.z;
#pragma unroll
  for (int rr = 0; rr < 4; rr++) {
    int n = n0 + ty + rr * 8, t = t0 + tx;
    tile[ty + rr * 8][tx] = (n < NN) ? x[((size_t)bc * NN + n) * 256 + t] : 0.f;
  }
  __syncthreads();
#pragma unroll
  for (int rr = 0; rr < 4; rr++) {
    int t = t0 + ty + rr * 8, n = n0 + tx;
    if (n < NN) xT[((size_t)bc * 256 + t) * NN + n] = tile[tx][ty + rr * 8];
  }
}

// ---------------------------------------------------------------------------
// B^T as f16 hi/lo pair: hi[w][v]+lo[w][v] ~= src[v][w], 512x512 zero-padded.
__global__ __launch_bounds__(256) void bt_kernel(const float* __restrict__ src,
                                                 f16* __restrict__ hi,
                                                 f16* __restrict__ lo) {
  int idx = blockIdx.x * 256 + threadIdx.x;  // 512*512 total
  int w = idx >> 9, v = idx & 511;
  float x = (w < NN && v < NN) ? src[v * NN + w] : 0.f;
  f16 h = (f16)x;
  hi[idx] = h;
  lo[idx] = (f16)(x - (float)h);
}

// ---------------------------------------------------------------------------
// Squared-matrix B^T pair: dst[w][v] = (src @ src)[v][w].
__global__ __launch_bounds__(512) void sq_kernel(const float* __restrict__ srcA,
                                                 const float* __restrict__ srcB,
                                                 f16* __restrict__ hiA, f16* __restrict__ loA,
                                                 f16* __restrict__ hiB, f16* __restrict__ loB) {
  const float* src = blockIdx.y == 0 ? srcA : srcB;
  f16* hi = blockIdx.y == 0 ? hiA : hiB;
  f16* lo = blockIdx.y == 0 ? loA : loB;
  int v = blockIdx.x;   // 0..511
  int w = threadIdx.x;  // 0..511
  __shared__ float vrow[512];
  vrow[w] = (v < NN && w < NN) ? src[v * NN + w] : 0.f;
  __syncthreads();
  float acc = 0.f;
  if (v < NN && w < NN) {
#pragma unroll 4
    for (int u = 0; u < NN; u++) acc = fmaf(vrow[u], src[u * NN + w], acc);
  }
  size_t o = (size_t)w * 512 + v;
  f16 h = (f16)acc;
  hi[o] = h;
  lo[o] = (f16)(acc - (float)h);
}

// ---------------------------------------------------------------------------
// Zero pad columns [500,512) of the six f16 P arrays (ws re-poisoned 0xAA).
__global__ __launch_bounds__(256) void padzero_kernel(uint32_t* __restrict__ slab, int R) {
  int idx = blockIdx.x * 256 + threadIdx.x;
  int total = 6 * R * 6;
  if (idx >= total) return;
  int a = idx / (R * 6);
  int rem = idx - a * R * 6;
  int row = rem / 6;
  int q = rem - row * 6;
  slab[(size_t)a * R * 256 + (size_t)row * 256 + 250 + q] = 0u;
}

// ---------------------------------------------------------------------------
// Fused (start-conv) + dilated-conv + gating + GCN channel-mix. FG in registers.
// FUSED=true (layer 0): h comes from start-conv of xT on the fly.
// h residual stream fp32 (NOT bounded — carries A^2-path terms up to ~1e3;
// f16 storage failed round-8 with absmax 5.8). Single-pass dconv: 64 fully
// unrolled accumulators (the r1 "halves" split was a workaround for partial
// unroll, not true pressure; this halves hprev reads).
template <bool FUSED>
__global__ __launch_bounds__(256) void dcm_kernel(
    const float* __restrict__ hprev, const float* __restrict__ xT,
    const float* __restrict__ sw, const float* __restrict__ sb,
    const float* __restrict__ fw, const float* __restrict__ fb,
    const float* __restrict__ gw, const float* __restrict__ gb,
    const float* __restrict__ cw, const float* __restrict__ cb,
    float* __restrict__ Hout,
    f16* __restrict__ P1a,
    f16* __restrict__ P2aH, f16* __restrict__ P2aL,
    f16* __restrict__ P1b,
    f16* __restrict__ P2bH, f16* __restrict__ P2bL,
    float* __restrict__ tapL,
    int Lp, int L, int b0) {
  int nc = blockIdx.x, j = blockIdx.y, bb = blockIdx.z;
  int n = nc * 256 + threadIdx.x;
  if (n >= NN) return;
  size_t base = ((size_t)(bb * 32) * Lp + 2 * j) * NN + n;
  size_t cs = (size_t)Lp * NN;
  float x00 = 0.f, x01 = 0.f, x10 = 0.f, x11 = 0.f;
  if (FUSED) {
    const float* xb = xT + (size_t)(b0 + bb) * 2 * 256 * NN;
    x00 = xb[(size_t)(2 * j) * NN + n];
    x01 = xb[(size_t)(2 * j + 1) * NN + n];
    x10 = xb[(size_t)(256 + 2 * j) * NN + n];
    x11 = xb[(size_t)(256 + 2 * j + 1) * NN + n];
  }
  float accf[32], accg[32];
#pragma unroll
  for (int c = 0; c < 32; c++) {
    accf[c] = fb[c];
    accg[c] = gb[c];
  }
  for (int cp = 0; cp < 32; cp++) {
    float v0, v1;
    if (FUSED) {
      float w0 = sw[cp * 2], w1 = sw[cp * 2 + 1], bc = sb[cp];
      v0 = fmaf(w0, x00, fmaf(w1, x10, bc));
      v1 = fmaf(w0, x01, fmaf(w1, x11, bc));
    } else {
      v0 = hprev[base + cp * cs];
      v1 = hprev[base + cp * cs + NN];
    }
    const float* fwp = fw + cp * 2;  // [c][cp][tap]
    const float* gwp = gw + cp * 2;
#pragma unroll
    for (int c = 0; c < 32; c++) {
      accf[c] = fmaf(fwp[c * 64], v0, accf[c]);
      accf[c] = fmaf(fwp[c * 64 + 1], v1, accf[c]);
      accg[c] = fmaf(gwp[c * 64], v0, accg[c]);
      accg[c] = fmaf(gwp[c * 64 + 1], v1, accg[c]);
    }
  }
  float FG[32];
#pragma unroll
  for (int c = 0; c < 32; c++) {
    float E = __expf(2.f * accf[c]);
    float th = 1.f - 2.f / (E + 1.f);          // tanh
    float sg = 1.f / (1.f + __expf(-accg[c])); // sigmoid
    FG[c] = th * sg;
  }
  if (j == L - 1) {
    size_t tbase = ((size_t)(b0 + bb) * 32) * NN + n;
#pragma unroll
    for (int c = 0; c < 32; c++) tapL[tbase + (size_t)c * NN] = FG[c];
  }
  if (Hout == nullptr) return;  // layer 8: only the skip tap survives
#pragma unroll 2
  for (int c = 0; c < 32; c++) {
    const float* wr = cw + c * 160;
    float h = cb[c], p1 = 0.f, p2 = 0.f, q1 = 0.f, q2 = 0.f;
#pragma unroll
    for (int cp = 0; cp < 32; cp++) {
      float f = FG[cp];
      h  = fmaf(wr[cp], f, h);
      p1 = fmaf(wr[32 + cp], f, p1);
      p2 = fmaf(wr[64 + cp], f, p2);
      q1 = fmaf(wr[96 + cp], f, q1);
      q2 = fmaf(wr[128 + cp], f, q2);
    }
    // residual = hprev[2j+1] (start-conv output for layer 0)
    if (FUSED) {
      h += fmaf(sw[c * 2], x01, fmaf(sw[c * 2 + 1], x11, sb[c]));
    } else {
      h += hprev[((size_t)(bb * 32 + c) * Lp + 2 * j + 1) * NN + n];
    }
    size_t mi = (size_t)(bb * 32 + c) * L + j;
    Hout[mi * NN + n] = h;
    size_t o = mi * KP + n;
    f16 t;
    P1a[o] = (f16)p1;
    t = (f16)p2; P2aH[o] = t; P2aL[o] = (f16)(p2 - (float)t);
    P1b[o] = (f16)q1;
    t = (f16)q2; P2bH[o] = t; P2bL[o] = (f16)(q2 - (float)t);
  }
}

// ---------------------------------------------------------------------------
// GCN node-mix GEMM (verified 16x16x32 pipe). Block = 32m x 256n, 4 waves of
// 32m x 64n (2x4 subtiles), grid (M/32, 2): 1024 blocks at layer 0 ->
// 4 blocks/CU = 16 waves/CU (2x r7's latency hiding) at the cost of A read
// twice (~250 MB, ~40 us HBM). acc=32 VGPR/thread, ~92 total: no spill.
// Out[m,w] = BN(Cin[m,w] + sum_g A_g[m,:].(B1_g+B2_g)[w,:]), fp32 in-place.
__global__ __launch_bounds__(256) void mfma_gcn(MSet s,
    const float* __restrict__ Cin, float* __restrict__ Out, int M,
    const float* __restrict__ bng, const float* __restrict__ bnb, int lshift) {
  int tid = threadIdx.x;
  int wave = tid >> 6, lane = tid & 63;
  int m0 = blockIdx.x * 32;
  int n0 = blockIdx.y * 256 + wave * 64;
  int lm = lane & 15, kq = lane >> 4;  // operand frag: row lm, k-quad kq (8 k)
  floatx4 acc[2][4];
#pragma unroll
  for (int i = 0; i < 2; i++)
#pragma unroll
    for (int j = 0; j < 4; j++) acc[i][j] = (floatx4){0.f, 0.f, 0.f, 0.f};
  size_t arow[2], brow[4];
#pragma unroll
  for (int i = 0; i < 2; i++) arow[i] = (size_t)(m0 + i * 16 + lm) * KP + kq * 8;
#pragma unroll
  for (int j = 0; j < 4; j++) brow[j] = (size_t)(n0 + j * 16 + lm) * KP + kq * 8;

  for (int gi = 0; gi < 6; gi++) {
    const f16* __restrict__ Ap = s.A[gi];
    const f16* __restrict__ B1p = s.B1[gi];
    const f16* __restrict__ B2p = s.B2[gi];
    if (B2p != nullptr) {
      for (int k0 = 0; k0 < KP; k0 += 32) {
        half8 av[2], b1[4], b2[4];
#pragma unroll
        for (int i = 0; i < 2; i++) av[i] = *(const half8*)(Ap + arow[i] + k0);
#pragma unroll
        for (int j = 0; j < 4; j++) b1[j] = *(const half8*)(B1p + brow[j] + k0);
#pragma unroll
        for (int j = 0; j < 4; j++) b2[j] = *(const half8*)(B2p + brow[j] + k0);
#pragma unroll
        for (int i = 0; i < 2; i++)
#pragma unroll
          for (int j = 0; j < 4; j++)
            acc[i][j] = __builtin_amdgcn_mfma_f32_16x16x32_f16(av[i], b1[j], acc[i][j], 0, 0, 0);
#pragma unroll
        for (int i = 0; i < 2; i++)
#pragma unroll
          for (int j = 0; j < 4; j++)
            acc[i][j] = __builtin_amdgcn_mfma_f32_16x16x32_f16(av[i], b2[j], acc[i][j], 0, 0, 0);
      }
    } else {
      for (int k0 = 0; k0 < KP; k0 += 32) {
        half8 av[2], b1[4];
#pragma unroll
        for (int i = 0; i < 2; i++) av[i] = *(const half8*)(Ap + arow[i] + k0);
#pragma unroll
        for (int j = 0; j < 4; j++) b1[j] = *(const half8*)(B1p + brow[j] + k0);
#pragma unroll
        for (int i = 0; i < 2; i++)
#pragma unroll
          for (int j = 0; j < 4; j++)
            acc[i][j] = __builtin_amdgcn_mfma_f32_16x16x32_f16(av[i], b1[j], acc[i][j], 0, 0, 0);
      }
    }
  }
  // epilogue: C/D layout col = lane&15, row = (lane>>4)*4 + reg
  int cn = lane & 15, rq = lane >> 4;
  float rs = rsqrtf(1.f + 1e-5f);
#pragma unroll
  for (int i = 0; i < 2; i++) {
#pragma unroll
    for (int r = 0; r < 4; r++) {
      int row = m0 + i * 16 + rq * 4 + r;
      int c = (row >> lshift) & 31;  // m = (bb*32+c)*L + j
      float scale = bng[c] * rs;
      float bias = bnb[c];
#pragma unroll
      for (int j = 0; j < 4; j++) {
        int col = n0 + j * 16 + cn;
        if (col < NN) {
          size_t o = (size_t)row * NN + col;
          Out[o] = (acc[i][j][r] + Cin[o]) * scale + bias;
        }
      }
    }
  }
}

// ---------------------------------------------------------------------------
// skip -> relu -> end1 -> relu -> end2. One block per (b, 20 n-values).
#define NB 20
#define NBP 21
__global__ __launch_bounds__(256) void final_kernel(const float* __restrict__ tap,
    const float* __restrict__ skw, const float* __restrict__ skb,
    const float* __restrict__ e1w, const float* __restrict__ e1b,
    const float* __restrict__ e2w, const float* __restrict__ e2b,
    float* __restrict__ out) {
  __shared__ float tapS[256][NBP];
  __shared__ float skS[256][NBP];
  __shared__ float e1S[512][NBP];
  int tid = threadIdx.x;
  int b = blockIdx.y;
  int n0 = blockIdx.x * NB;
  {
    int i = tid >> 5, c = tid & 31;
    const float* tp = tap + (((size_t)i * 8 + b) * 32 + c) * NN + n0;
#pragma unroll
    for (int v = 0; v < NB; v++) tapS[tid][v] = tp[v];
  }
  __syncthreads();
  {
    float bsum = 0.f;
#pragma unroll
    for (int i2 = 0; i2 < 8; i2++) bsum += skb[i2 * 256 + tid];
    float acc[NB];
#pragma unroll
    for (int v = 0; v < NB; v++) acc[v] = bsum;
#pragma unroll
    for (int i2 = 0; i2 < 8; i2++) {
      const float* wr = skw + ((size_t)i2 * 256 + tid) * 32;
#pragma unroll
      for (int cp = 0; cp < 32; cp++) {
        float w = wr[cp];
#pragma unroll
        for (int v = 0; v < NB; v++) acc[v] = fmaf(w, tapS[i2 * 32 + cp][v], acc[v]);
      }
    }
#pragma unroll
    for (int v = 0; v < NB; v++) skS[tid][v] = fmaxf(acc[v], 0.f);
  }
  __syncthreads();
#pragma unroll
  for (int h = 0; h < 2; h++) {
    int k = tid + h * 256;
    float bv = e1b[k];
    float acc[NB];
#pragma unroll
    for (int v = 0; v < NB; v++) acc[v] = bv;
    const float* wr = e1w + (size_t)k * 256;
    for (int o = 0; o < 256; o++) {
      float w = wr[o];
#pragma unroll
      for (int v = 0; v < NB; v++) acc[v] = fmaf(w, skS[o][v], acc[v]);
    }
#pragma unroll
    for (int v = 0; v < NB; v++) e1S[k][v] = fmaxf(acc[v], 0.f);
  }
  __syncthreads();
  if (tid < 12 * NB) {
    int q = tid / NB, v = tid % NB;
    float acc = e2b[q];
    const float* wr = e2w + (size_t)q * 512;
#pragma unroll 8
    for (int k = 0; k < 512; k++) acc = fmaf(wr[k], e1S[k][v], acc);
    out[((size_t)b * 12 + q) * NN + n0 + v] = acc;
  }
}

// ---------------------------------------------------------------------------
extern "C" void kernel_launch(void* const* d_in, const int* in_sizes, int n_in,
                              void* d_out, int out_size, void* d_ws, size_t ws_size,
                              hipStream_t stream) {
  const float* x       = (const float*)d_in[0];
  const float* A0      = (const float*)d_in[1];
  const float* start_w = (const float*)d_in[2];
  const float* start_b = (const float*)d_in[3];
  const float* filt_w  = (const float*)d_in[4];
  const float* filt_b  = (const float*)d_in[5];
  const float* gate_w  = (const float*)d_in[6];
  const float* gate_b  = (const float*)d_in[7];
  const float* skip_w  = (const float*)d_in[8];
  const float* skip_b  = (const float*)d_in[9];
  const float* gcn_w   = (const float*)d_in[10];
  const float* gcn_b   = (const float*)d_in[11];
  const float* bn_g    = (const float*)d_in[12];
  const float* bn_b    = (const float*)d_in[13];
  const float* nv1     = (const float*)d_in[14];
  const float* nv2     = (const float*)d_in[15];
  const float* e1w     = (const float*)d_in[16];
  const float* e1b     = (const float*)d_in[17];
  const float* e2w     = (const float*)d_in[18];
  const float* e2b     = (const float*)d_in[19];
  float* out = (float*)d_out;

  char* ws = (char*)d_ws;
  size_t off = 0;
  auto alloc = [&](size_t bytes) -> void* {
    void* p = (void*)(ws + off);
    off += (bytes + 255) & ~(size_t)255;
    return p;
  };
  float* adp   = (float*)alloc((size_t)NN * NN * 4);
  float* tap   = (float*)alloc((size_t)8 * 8 * 32 * NN * 4);
  float* xT    = (float*)alloc((size_t)16 * 256 * NN * 4);  // [b*2+ch][t][n]
  f16*   A0tH  = (f16*)alloc((size_t)KP * KP * 2);
  f16*   A0tL  = (f16*)alloc((size_t)KP * KP * 2);
  f16*   adptH = (f16*)alloc((size_t)KP * KP * 2);
  f16*   adptL = (f16*)alloc((size_t)KP * KP * 2);
  f16*   Q0H   = (f16*)alloc((size_t)KP * KP * 2);   // (A0^2)^T pair
  f16*   Q0L   = (f16*)alloc((size_t)KP * KP * 2);
  f16*   QdH   = (f16*)alloc((size_t)KP * KP * 2);   // (adp^2)^T pair
  f16*   QdL   = (f16*)alloc((size_t)KP * KP * 2);
  size_t fixed = off;
  // per-batch: h128 (L<=128) + h64 (L<=64) fp32 + 6 f16 P arrays [32*128 x 512]
  const size_t perg = 8192000ull + 4096000ull + 6ull * 4194304ull;  // 37.45 MB
  int g = 8;
  while (g > 1 && fixed + (size_t)g * perg + 1048576 > ws_size) g >>= 1;
  float* h128 = (float*)alloc((size_t)g * 8192000ull);
  float* h64  = (float*)alloc((size_t)g * 4096000ull);
  f16* slab   = (f16*)alloc(6ull * g * 4194304ull);
  int R = g * 4096;  // rows per f16 array (layer-0 M)
  f16* P1a  = slab + 0ull * R * KP;
  f16* P2aH = slab + 1ull * R * KP;
  f16* P2aL = slab + 2ull * R * KP;
  f16* P1b  = slab + 3ull * R * KP;
  f16* P2bH = slab + 4ull * R * KP;
  f16* P2bL = slab + 5ull * R * KP;

  adp_kernel<<<NN, 256, 0, stream>>>(nv1, nv2, adp);
  xt_kernel<<<dim3(16, 8, 16), 256, 0, stream>>>(x, xT);
  bt_kernel<<<1024, 256, 0, stream>>>(A0, A0tH, A0tL);
  bt_kernel<<<1024, 256, 0, stream>>>(adp, adptH, adptL);
  sq_kernel<<<dim3(512, 2), 512, 0, stream>>>(A0, adp, Q0H, Q0L, QdH, QdL);
  padzero_kernel<<<(36 * R + 255) / 256, 256, 0, stream>>>((uint32_t*)slab, R);

  // out = H + P1a*A0 + P2a*A0^2 + P1b*adp + P2b*adp^2; P2 terms as hi/lo
  // pairs (3 passes, lo*lo dropped), P1 terms single-f16 (2 passes).
  MSet s{};
  s.A[0] = P1a;  s.B1[0] = A0tH;  s.B2[0] = A0tL;
  s.A[1] = P2aH; s.B1[1] = Q0H;   s.B2[1] = Q0L;
  s.A[2] = P2aL; s.B1[2] = Q0H;   s.B2[2] = nullptr;
  s.A[3] = P1b;  s.B1[3] = adptH; s.B2[3] = adptL;
  s.A[4] = P2bH; s.B1[4] = QdH;   s.B2[4] = QdL;
  s.A[5] = P2bL; s.B1[5] = QdH;   s.B2[5] = nullptr;

  for (int b0 = 0; b0 < 8; b0 += g) {
    float* hprev = nullptr;
    int Lp = 256;
    for (int i = 0; i < 8; i++) {
      int L = Lp >> 1;  // 128,64,...,1
      if (i < 7) {
        float* hout = (i & 1) ? h64 : h128;
        if (i == 0) {
          dcm_kernel<true><<<dim3(2, L, g), 256, 0, stream>>>(
              nullptr, xT, start_w, start_b,
              filt_w + i * 2048, filt_b + i * 32, gate_w + i * 2048, gate_b + i * 32,
              gcn_w + i * 5120, gcn_b + i * 32, hout,
              P1a, P2aH, P2aL, P1b, P2bH, P2bL,
              tap + (size_t)i * 8 * 32 * NN, Lp, L, b0);
        } else {
          dcm_kernel<false><<<dim3(2, L, g), 256, 0, stream>>>(
              hprev, nullptr, nullptr, nullptr,
              filt_w + i * 2048, filt_b + i * 32, gate_w + i * 2048, gate_b + i * 32,
              gcn_w + i * 5120, gcn_b + i * 32, hout,
              P1a, P2aH, P2aL, P1b, P2bH, P2bL,
              tap + (size_t)i * 8 * 32 * NN, Lp, L, b0);
        }
        int M = g * 32 * L;
        mfma_gcn<<<dim3(M / 32, 2), 256, 0, stream>>>(s, hout, hout, M,
                                                      bn_g + i * 32, bn_b + i * 32, 7 - i);
        hprev = hout;
        Lp = L;
      } else {
        // layer 8: only the skip tap survives
        dcm_kernel<false><<<dim3(2, 1, g), 256, 0, stream>>>(
            hprev, nullptr, nullptr, nullptr,
            filt_w + i * 2048, filt_b + i * 32, gate_w + i * 2048, gate_b + i * 32,
            gcn_w, gcn_b, nullptr,
            P1a, P2aH, P2aL, P1b, P2bH, P2bL,
            tap + (size_t)i * 8 * 32 * NN, Lp, 1, b0);
      }
    }
  }
  final_kernel<<<dim3(25, 8), 256, 0, stream>>>(tap, skip_w, skip_b, e1w, e1b, e2w, e2b, out);
}

// Round 10
// 3961.481 us; speedup vs baseline: 1.3793x; 1.1499x over previous
//
#include <hip/hip_runtime.h>
#include <cstdint>
#include <cstddef>

#define NN 500
#define KP 512   // node dim padded to 512 for f16 MFMA operands

typedef _Float16 f16;
typedef _Float16 half8 __attribute__((ext_vector_type(8)));
typedef float floatx4 __attribute__((ext_vector_type(4)));

// 10 flattened GEMM passes: acc += A[p] * B[p]^T.
struct PassSet {
  const f16* A[10];
  const f16* B[10];
};

// ---------------------------------------------------------------------------
// adp = softmax(relu(E1 @ E2), axis=1)
__global__ __launch_bounds__(256) void adp_kernel(const float* __restrict__ e1,
                                                  const float* __restrict__ e2,
                                                  float* __restrict__ adp) {
  int r = blockIdx.x;
  int tid = threadIdx.x;
  __shared__ float red[256];
  __shared__ float e1row[16];
  if (tid < 10) e1row[tid] = e1[r * 10 + tid];
  __syncthreads();
  float z0, z1 = 0.f;
  {
    float acc = 0.f;
#pragma unroll
    for (int k = 0; k < 10; k++) acc += e1row[k] * e2[k * NN + tid];
    z0 = fmaxf(acc, 0.f);
  }
  bool has1 = (tid + 256) < NN;
  if (has1) {
    float acc = 0.f;
#pragma unroll
    for (int k = 0; k < 10; k++) acc += e1row[k] * e2[k * NN + tid + 256];
    z1 = fmaxf(acc, 0.f);
  }
  float mx = has1 ? fmaxf(z0, z1) : z0;
  red[tid] = mx;
  __syncthreads();
  for (int s = 128; s > 0; s >>= 1) {
    if (tid < s) red[tid] = fmaxf(red[tid], red[tid + s]);
    __syncthreads();
  }
  mx = red[0];
  __syncthreads();
  float ex0 = __expf(z0 - mx);
  float ex1 = has1 ? __expf(z1 - mx) : 0.f;
  red[tid] = ex0 + ex1;
  __syncthreads();
  for (int s = 128; s > 0; s >>= 1) {
    if (tid < s) red[tid] += red[tid + s];
    __syncthreads();
  }
  float inv = 1.f / red[0];
  adp[r * NN + tid] = ex0 * inv;
  if (has1) adp[r * NN + tid + 256] = ex1 * inv;
}

// ---------------------------------------------------------------------------
// xT[bc][t][n] = x[bc][n][t]  (coalesced reads for the fused layer-0 dconv)
__global__ __launch_bounds__(256) void xt_kernel(const float* __restrict__ x,
                                                 float* __restrict__ xT) {
  __shared__ float tile[32][33];
  int tx = threadIdx.x & 31, ty = threadIdx.x >> 5;
  int n0 = blockIdx.x * 32, t0 = blockIdx.y * 32, bc = blockIdx.z;
#pragma unroll
  for (int rr = 0; rr < 4; rr++) {
    int n = n0 + ty + rr * 8, t = t0 + tx;
    tile[ty + rr * 8][tx] = (n < NN) ? x[((size_t)bc * NN + n) * 256 + t] : 0.f;
  }
  __syncthreads();
#pragma unroll
  for (int rr = 0; rr < 4; rr++) {
    int t = t0 + ty + rr * 8, n = n0 + tx;
    if (n < NN) xT[((size_t)bc * 256 + t) * NN + n] = tile[tx][ty + rr * 8];
  }
}

// ---------------------------------------------------------------------------
// B^T as f16 hi/lo pair: hi[w][v]+lo[w][v] ~= src[v][w], 512x512 zero-padded.
__global__ __launch_bounds__(256) void bt_kernel(const float* __restrict__ src,
                                                 f16* __restrict__ hi,
                                                 f16* __restrict__ lo) {
  int idx = blockIdx.x * 256 + threadIdx.x;  // 512*512 total
  int w = idx >> 9, v = idx & 511;
  float x = (w < NN && v < NN) ? src[v * NN + w] : 0.f;
  f16 h = (f16)x;
  hi[idx] = h;
  lo[idx] = (f16)(x - (float)h);
}

// ---------------------------------------------------------------------------
// Squared-matrix B^T pair: dst[w][v] = (src @ src)[v][w].
__global__ __launch_bounds__(512) void sq_kernel(const float* __restrict__ srcA,
                                                 const float* __restrict__ srcB,
                                                 f16* __restrict__ hiA, f16* __restrict__ loA,
                                                 f16* __restrict__ hiB, f16* __restrict__ loB) {
  const float* src = blockIdx.y == 0 ? srcA : srcB;
  f16* hi = blockIdx.y == 0 ? hiA : hiB;
  f16* lo = blockIdx.y == 0 ? loA : loB;
  int v = blockIdx.x;   // 0..511
  int w = threadIdx.x;  // 0..511
  __shared__ float vrow[512];
  vrow[w] = (v < NN && w < NN) ? src[v * NN + w] : 0.f;
  __syncthreads();
  float acc = 0.f;
  if (v < NN && w < NN) {
#pragma unroll 4
    for (int u = 0; u < NN; u++) acc = fmaf(vrow[u], src[u * NN + w], acc);
  }
  size_t o = (size_t)w * 512 + v;
  f16 h = (f16)acc;
  hi[o] = h;
  lo[o] = (f16)(acc - (float)h);
}

// ---------------------------------------------------------------------------
// Zero pad columns [500,512) of the six f16 P arrays (ws re-poisoned 0xAA).
__global__ __launch_bounds__(256) void padzero_kernel(uint32_t* __restrict__ slab, int R) {
  int idx = blockIdx.x * 256 + threadIdx.x;
  int total = 6 * R * 6;
  if (idx >= total) return;
  int a = idx / (R * 6);
  int rem = idx - a * R * 6;
  int row = rem / 6;
  int q = rem - row * 6;
  slab[(size_t)a * R * 256 + (size_t)row * 256 + 250 + q] = 0u;
}

// ---------------------------------------------------------------------------
// Fused (start-conv) + dilated-conv + gating + GCN channel-mix. FG in registers.
// FUSED=true (layer 0): h comes from start-conv of xT on the fly.
// h residual stream fp32 (carries A^2-path terms up to ~1e3; f16 failed r8).
// All register-array index loops fully unrolled (scratch-demotion hazard, r1).
template <bool FUSED>
__global__ __launch_bounds__(256) void dcm_kernel(
    const float* __restrict__ hprev, const float* __restrict__ xT,
    const float* __restrict__ sw, const float* __restrict__ sb,
    const float* __restrict__ fw, const float* __restrict__ fb,
    const float* __restrict__ gw, const float* __restrict__ gb,
    const float* __restrict__ cw, const float* __restrict__ cb,
    float* __restrict__ Hout,
    f16* __restrict__ P1a,
    f16* __restrict__ P2aH, f16* __restrict__ P2aL,
    f16* __restrict__ P1b,
    f16* __restrict__ P2bH, f16* __restrict__ P2bL,
    float* __restrict__ tapL,
    int Lp, int L, int b0) {
  int nc = blockIdx.x, j = blockIdx.y, bb = blockIdx.z;
  int n = nc * 256 + threadIdx.x;
  if (n >= NN) return;
  size_t base = ((size_t)(bb * 32) * Lp + 2 * j) * NN + n;
  size_t cs = (size_t)Lp * NN;
  float x00 = 0.f, x01 = 0.f, x10 = 0.f, x11 = 0.f;
  if (FUSED) {
    const float* xb = xT + (size_t)(b0 + bb) * 2 * 256 * NN;
    x00 = xb[(size_t)(2 * j) * NN + n];
    x01 = xb[(size_t)(2 * j + 1) * NN + n];
    x10 = xb[(size_t)(256 + 2 * j) * NN + n];
    x11 = xb[(size_t)(256 + 2 * j + 1) * NN + n];
  }
  float accf[32], accg[32];
#pragma unroll
  for (int c = 0; c < 32; c++) {
    accf[c] = fb[c];
    accg[c] = gb[c];
  }
  for (int cp = 0; cp < 32; cp++) {
    float v0, v1;
    if (FUSED) {
      float w0 = sw[cp * 2], w1 = sw[cp * 2 + 1], bc = sb[cp];
      v0 = fmaf(w0, x00, fmaf(w1, x10, bc));
      v1 = fmaf(w0, x01, fmaf(w1, x11, bc));
    } else {
      v0 = hprev[base + cp * cs];
      v1 = hprev[base + cp * cs + NN];
    }
    const float* fwp = fw + cp * 2;  // [c][cp][tap]
    const float* gwp = gw + cp * 2;
#pragma unroll
    for (int c = 0; c < 32; c++) {
      accf[c] = fmaf(fwp[c * 64], v0, accf[c]);
      accf[c] = fmaf(fwp[c * 64 + 1], v1, accf[c]);
      accg[c] = fmaf(gwp[c * 64], v0, accg[c]);
      accg[c] = fmaf(gwp[c * 64 + 1], v1, accg[c]);
    }
  }
  float FG[32];
#pragma unroll
  for (int c = 0; c < 32; c++) {
    float E = __expf(2.f * accf[c]);
    float th = 1.f - 2.f / (E + 1.f);          // tanh
    float sg = 1.f / (1.f + __expf(-accg[c])); // sigmoid
    FG[c] = th * sg;
  }
  if (j == L - 1) {
    size_t tbase = ((size_t)(b0 + bb) * 32) * NN + n;
#pragma unroll
    for (int c = 0; c < 32; c++) tapL[tbase + (size_t)c * NN] = FG[c];
  }
  if (Hout == nullptr) return;  // layer 8: only the skip tap survives
#pragma unroll 2
  for (int c = 0; c < 32; c++) {
    const float* wr = cw + c * 160;
    float h = cb[c], p1 = 0.f, p2 = 0.f, q1 = 0.f, q2 = 0.f;
#pragma unroll
    for (int cp = 0; cp < 32; cp++) {
      float f = FG[cp];
      h  = fmaf(wr[cp], f, h);
      p1 = fmaf(wr[32 + cp], f, p1);
      p2 = fmaf(wr[64 + cp], f, p2);
      q1 = fmaf(wr[96 + cp], f, q1);
      q2 = fmaf(wr[128 + cp], f, q2);
    }
    // residual = hprev[2j+1] (start-conv output for layer 0)
    if (FUSED) {
      h += fmaf(sw[c * 2], x01, fmaf(sw[c * 2 + 1], x11, sb[c]));
    } else {
      h += hprev[((size_t)(bb * 32 + c) * Lp + 2 * j + 1) * NN + n];
    }
    size_t mi = (size_t)(bb * 32 + c) * L + j;
    Hout[mi * NN + n] = h;
    size_t o = mi * KP + n;
    f16 t;
    P1a[o] = (f16)p1;
    t = (f16)p2; P2aH[o] = t; P2aL[o] = (f16)(p2 - (float)t);
    P1b[o] = (f16)q1;
    t = (f16)q2; P2bH[o] = t; P2bL[o] = (f16)(q2 - (float)t);
  }
}

// ---------------------------------------------------------------------------
// LDS-staged GCN node-mix GEMM (m97-style 2-barrier K-loop + register
// prefetch). Block 128m x 128n, 4 waves of 64x64 (4x4 subtiles of 16x16x32,
// acc=64 VGPR). LDS tiles 128x40 f16 (row pad 32->40: staging writes land
// 2-way bank-aliased = free, frag reads 2-way = free). Next 32-k strip is
// prefetched into 16 VGPRs right after the staging barrier so its L2 latency
// hides under the ds_read+MFMA phase. Pass loop fully unrolled -> all
// pointers static (SGPRs). Out = BN(Cin + sum_p A_p . B_p), fp32 in-place.
__global__ __launch_bounds__(256) void mfma_gcn(PassSet s,
    const float* __restrict__ Cin, float* __restrict__ Out, int M,
    const float* __restrict__ bng, const float* __restrict__ bnb, int lshift) {
  __shared__ f16 As[128 * 40];
  __shared__ f16 Bs[128 * 40];
  int tid = threadIdx.x;
  int wave = tid >> 6, lane = tid & 63;
  int wm = wave >> 1, wn = wave & 1;
  int m0 = blockIdx.x * 128;
  int n0 = blockIdx.y * 128;
  int lm = lane & 15, kq = lane >> 4;  // frag: row lm, k-quad kq (8 k)
  // staging: thread covers rows (tid>>2) and (tid>>2)+64, 16B chunk tid&3
  int srow = tid >> 2, sc = tid & 3;
  int ar0 = m0 + srow;      if (ar0 > M - 1) ar0 = M - 1;
  int ar1 = m0 + srow + 64; if (ar1 > M - 1) ar1 = M - 1;
  size_t ag0 = (size_t)ar0 * KP + sc * 8;
  size_t ag1 = (size_t)ar1 * KP + sc * 8;
  size_t bg0 = (size_t)(n0 + srow) * KP + sc * 8;
  size_t bg1 = (size_t)(n0 + srow + 64) * KP + sc * 8;
  int sl0 = srow * 40 + sc * 8;
  int sl1 = (srow + 64) * 40 + sc * 8;

  floatx4 acc[4][4];
#pragma unroll
  for (int i = 0; i < 4; i++)
#pragma unroll
    for (int j = 0; j < 4; j++) acc[i][j] = (floatx4){0.f, 0.f, 0.f, 0.f};

  float4 pa0, pa1, pb0, pb1;
  {
    const f16* Ap = s.A[0];
    const f16* Bp = s.B[0];
    pa0 = *(const float4*)(Ap + ag0);
    pa1 = *(const float4*)(Ap + ag1);
    pb0 = *(const float4*)(Bp + bg0);
    pb1 = *(const float4*)(Bp + bg1);
  }
#pragma unroll
  for (int p = 0; p < 10; p++) {
    const f16* __restrict__ Ap = s.A[p];
    const f16* __restrict__ Bp = s.B[p];
    const f16* __restrict__ Apn = s.A[p < 9 ? p + 1 : p];
    const f16* __restrict__ Bpn = s.B[p < 9 ? p + 1 : p];
    for (int k0 = 0; k0 < KP; k0 += 32) {
      __syncthreads();  // prior compute done reading LDS
      *(float4*)(As + sl0) = pa0;
      *(float4*)(As + sl1) = pa1;
      *(float4*)(Bs + sl0) = pb0;
      *(float4*)(Bs + sl1) = pb1;
      __syncthreads();  // staging visible
      {  // prefetch next strip; latency overlaps the compute below
        bool lastk = (k0 == KP - 32);
        const f16* An = lastk ? Apn : Ap;
        const f16* Bn = lastk ? Bpn : Bp;
        int kn = lastk ? 0 : k0 + 32;
        pa0 = *(const float4*)(An + ag0 + kn);
        pa1 = *(const float4*)(An + ag1 + kn);
        pb0 = *(const float4*)(Bn + bg0 + kn);
        pb1 = *(const float4*)(Bn + bg1 + kn);
      }
      half8 a[4];
#pragma unroll
      for (int i = 0; i < 4; i++)
        a[i] = *(const half8*)(As + (wm * 64 + i * 16 + lm) * 40 + kq * 8);
#pragma unroll
      for (int j = 0; j < 4; j++) {
        half8 b = *(const half8*)(Bs + (wn * 64 + j * 16 + lm) * 40 + kq * 8);
#pragma unroll
        for (int i = 0; i < 4; i++)
          acc[i][j] = __builtin_amdgcn_mfma_f32_16x16x32_f16(a[i], b, acc[i][j], 0, 0, 0);
      }
    }
  }
  // epilogue: C/D layout col = lane&15, row = (lane>>4)*4 + reg
  int cn = lane & 15, rq = lane >> 4;
  float rs = rsqrtf(1.f + 1e-5f);
#pragma unroll
  for (int i = 0; i < 4; i++) {
#pragma unroll
    for (int r = 0; r < 4; r++) {
      int row = m0 + wm * 64 + i * 16 + rq * 4 + r;
      if (row < M) {
        int c = (row >> lshift) & 31;  // m = (bb*32+c)*L + j
        float scale = bng[c] * rs;
        float bias = bnb[c];
#pragma unroll
        for (int j = 0; j < 4; j++) {
          int col = n0 + wn * 64 + j * 16 + cn;
          if (col < NN) {
            size_t o = (size_t)row * NN + col;
            Out[o] = (acc[i][j][r] + Cin[o]) * scale + bias;
          }
        }
      }
    }
  }
}

// ---------------------------------------------------------------------------
// skip -> relu -> end1 -> relu -> end2. One block per (b, 20 n-values).
#define NB 20
#define NBP 21
__global__ __launch_bounds__(256) void final_kernel(const float* __restrict__ tap,
    const float* __restrict__ skw, const float* __restrict__ skb,
    const float* __restrict__ e1w, const float* __restrict__ e1b,
    const float* __restrict__ e2w, const float* __restrict__ e2b,
    float* __restrict__ out) {
  __shared__ float tapS[256][NBP];
  __shared__ float skS[256][NBP];
  __shared__ float e1S[512][NBP];
  int tid = threadIdx.x;
  int b = blockIdx.y;
  int n0 = blockIdx.x * NB;
  {
    int i = tid >> 5, c = tid & 31;
    const float* tp = tap + (((size_t)i * 8 + b) * 32 + c) * NN + n0;
#pragma unroll
    for (int v = 0; v < NB; v++) tapS[tid][v] = tp[v];
  }
  __syncthreads();
  {
    float bsum = 0.f;
#pragma unroll
    for (int i2 = 0; i2 < 8; i2++) bsum += skb[i2 * 256 + tid];
    float acc[NB];
#pragma unroll
    for (int v = 0; v < NB; v++) acc[v] = bsum;
#pragma unroll
    for (int i2 = 0; i2 < 8; i2++) {
      const float* wr = skw + ((size_t)i2 * 256 + tid) * 32;
#pragma unroll
      for (int cp = 0; cp < 32; cp++) {
        float w = wr[cp];
#pragma unroll
        for (int v = 0; v < NB; v++) acc[v] = fmaf(w, tapS[i2 * 32 + cp][v], acc[v]);
      }
    }
#pragma unroll
    for (int v = 0; v < NB; v++) skS[tid][v] = fmaxf(acc[v], 0.f);
  }
  __syncthreads();
#pragma unroll
  for (int h = 0; h < 2; h++) {
    int k = tid + h * 256;
    float bv = e1b[k];
    float acc[NB];
#pragma unroll
    for (int v = 0; v < NB; v++) acc[v] = bv;
    const float* wr = e1w + (size_t)k * 256;
    for (int o = 0; o < 256; o++) {
      float w = wr[o];
#pragma unroll
      for (int v = 0; v < NB; v++) acc[v] = fmaf(w, skS[o][v], acc[v]);
    }
#pragma unroll
    for (int v = 0; v < NB; v++) e1S[k][v] = fmaxf(acc[v], 0.f);
  }
  __syncthreads();
  if (tid < 12 * NB) {
    int q = tid / NB, v = tid % NB;
    float acc = e2b[q];
    const float* wr = e2w + (size_t)q * 512;
#pragma unroll 8
    for (int k = 0; k < 512; k++) acc = fmaf(wr[k], e1S[k][v], acc);
    out[((size_t)b * 12 + q) * NN + n0 + v] = acc;
  }
}

// ---------------------------------------------------------------------------
extern "C" void kernel_launch(void* const* d_in, const int* in_sizes, int n_in,
                              void* d_out, int out_size, void* d_ws, size_t ws_size,
                              hipStream_t stream) {
  const float* x       = (const float*)d_in[0];
  const float* A0      = (const float*)d_in[1];
  const float* start_w = (const float*)d_in[2];
  const float* start_b = (const float*)d_in[3];
  const float* filt_w  = (const float*)d_in[4];
  const float* filt_b  = (const float*)d_in[5];
  const float* gate_w  = (const float*)d_in[6];
  const float* gate_b  = (const float*)d_in[7];
  const float* skip_w  = (const float*)d_in[8];
  const float* skip_b  = (const float*)d_in[9];
  const float* gcn_w   = (const float*)d_in[10];
  const float* gcn_b   = (const float*)d_in[11];
  const float* bn_g    = (const float*)d_in[12];
  const float* bn_b    = (const float*)d_in[13];
  const float* nv1     = (const float*)d_in[14];
  const float* nv2     = (const float*)d_in[15];
  const float* e1w     = (const float*)d_in[16];
  const float* e1b     = (const float*)d_in[17];
  const float* e2w     = (const float*)d_in[18];
  const float* e2b     = (const float*)d_in[19];
  float* out = (float*)d_out;

  char* ws = (char*)d_ws;
  size_t off = 0;
  auto alloc = [&](size_t bytes) -> void* {
    void* p = (void*)(ws + off);
    off += (bytes + 255) & ~(size_t)255;
    return p;
  };
  float* adp   = (float*)alloc((size_t)NN * NN * 4);
  float* tap   = (float*)alloc((size_t)8 * 8 * 32 * NN * 4);
  float* xT    = (float*)alloc((size_t)16 * 256 * NN * 4);  // [b*2+ch][t][n]
  f16*   A0tH  = (f16*)alloc((size_t)KP * KP * 2);
  f16*   A0tL  = (f16*)alloc((size_t)KP * KP * 2);
  f16*   adptH = (f16*)alloc((size_t)KP * KP * 2);
  f16*   adptL = (f16*)alloc((size_t)KP * KP * 2);
  f16*   Q0H   = (f16*)alloc((size_t)KP * KP * 2);   // (A0^2)^T pair
  f16*   Q0L   = (f16*)alloc((size_t)KP * KP * 2);
  f16*   QdH   = (f16*)alloc((size_t)KP * KP * 2);   // (adp^2)^T pair
  f16*   QdL   = (f16*)alloc((size_t)KP * KP * 2);
  size_t fixed = off;
  // per-batch: h128 (L<=128) + h64 (L<=64) fp32 + 6 f16 P arrays [32*128 x 512]
  const size_t perg = 8192000ull + 4096000ull + 6ull * 4194304ull;  // 37.45 MB
  int g = 8;
  while (g > 1 && fixed + (size_t)g * perg + 1048576 > ws_size) g >>= 1;
  float* h128 = (float*)alloc((size_t)g * 8192000ull);
  float* h64  = (float*)alloc((size_t)g * 4096000ull);
  f16* slab   = (f16*)alloc(6ull * g * 4194304ull);
  int R = g * 4096;  // rows per f16 array (layer-0 M)
  f16* P1a  = slab + 0ull * R * KP;
  f16* P2aH = slab + 1ull * R * KP;
  f16* P2aL = slab + 2ull * R * KP;
  f16* P1b  = slab + 3ull * R * KP;
  f16* P2bH = slab + 4ull * R * KP;
  f16* P2bL = slab + 5ull * R * KP;

  adp_kernel<<<NN, 256, 0, stream>>>(nv1, nv2, adp);
  xt_kernel<<<dim3(16, 8, 16), 256, 0, stream>>>(x, xT);
  bt_kernel<<<1024, 256, 0, stream>>>(A0, A0tH, A0tL);
  bt_kernel<<<1024, 256, 0, stream>>>(adp, adptH, adptL);
  sq_kernel<<<dim3(512, 2), 512, 0, stream>>>(A0, adp, Q0H, Q0L, QdH, QdL);
  padzero_kernel<<<(36 * R + 255) / 256, 256, 0, stream>>>((uint32_t*)slab, R);

  // out = H + P1a*A0 + P2a*A0^2 + P1b*adp + P2b*adp^2; P2 terms as hi/lo
  // pairs (3 passes, lo*lo dropped), P1 terms single-f16 (2 passes).
  // Flattened to 10 (A,B) passes (same arithmetic/order as round 9).
  PassSet ps{};
  {
    const f16* Alist[10] = {P1a, P1a, P2aH, P2aH, P2aL, P1b, P1b, P2bH, P2bH, P2bL};
    const f16* Blist[10] = {A0tH, A0tL, Q0H, Q0L, Q0H, adptH, adptL, QdH, QdL, QdH};
    for (int q = 0; q < 10; q++) { ps.A[q] = Alist[q]; ps.B[q] = Blist[q]; }
  }

  for (int b0 = 0; b0 < 8; b0 += g) {
    float* hprev = nullptr;
    int Lp = 256;
    for (int i = 0; i < 8; i++) {
      int L = Lp >> 1;  // 128,64,...,1
      if (i < 7) {
        float* hout = (i & 1) ? h64 : h128;
        if (i == 0) {
          dcm_kernel<true><<<dim3(2, L, g), 256, 0, stream>>>(
              nullptr, xT, start_w, start_b,
              filt_w + i * 2048, filt_b + i * 32, gate_w + i * 2048, gate_b + i * 32,
              gcn_w + i * 5120, gcn_b + i * 32, hout,
              P1a, P2aH, P2aL, P1b, P2bH, P2bL,
              tap + (size_t)i * 8 * 32 * NN, Lp, L, b0);
        } else {
          dcm_kernel<false><<<dim3(2, L, g), 256, 0, stream>>>(
              hprev, nullptr, nullptr, nullptr,
              filt_w + i * 2048, filt_b + i * 32, gate_w + i * 2048, gate_b + i * 32,
              gcn_w + i * 5120, gcn_b + i * 32, hout,
              P1a, P2aH, P2aL, P1b, P2bH, P2bL,
              tap + (size_t)i * 8 * 32 * NN, Lp, L, b0);
        }
        int M = g * 32 * L;
        int Mb = (M + 127) / 128;
        mfma_gcn<<<dim3(Mb, 4), 256, 0, stream>>>(ps, hout, hout, M,
                                                  bn_g + i * 32, bn_b + i * 32, 7 - i);
        hprev = hout;
        Lp = L;
      } else {
        // layer 8: only the skip tap survives
        dcm_kernel<false><<<dim3(2, 1, g), 256, 0, stream>>>(
            hprev, nullptr, nullptr, nullptr,
            filt_w + i * 2048, filt_b + i * 32, gate_w + i * 2048, gate_b + i * 32,
            gcn_w, gcn_b, nullptr,
            P1a, P2aH, P2aL, P1b, P2bH, P2bL,
            tap + (size_t)i * 8 * 32 * NN, Lp, 1, b0);
      }
    }
  }
  final_kernel<<<dim3(25, 8), 256, 0, stream>>>(tap, skip_w, skip_b, e1w, e1b, e2w, e2b, out);
}

// Round 11
// 3768.809 us; speedup vs baseline: 1.4498x; 1.0511x over previous
//
#include <hip/hip_runtime.h>
#include <cstdint>
#include <cstddef>

#define NN 500
#define KP 512   // node dim padded to 512 for f16 MFMA operands

typedef _Float16 f16;
typedef _Float16 half8 __attribute__((ext_vector_type(8)));
typedef float floatx4 __attribute__((ext_vector_type(4)));

// 10 flattened GEMM passes: acc += A[p] * B[p]^T.
struct PassSet {
  const f16* A[10];
  const f16* B[10];
};

// ---------------------------------------------------------------------------
// adp = softmax(relu(E1 @ E2), axis=1)
__global__ __launch_bounds__(256) void adp_kernel(const float* __restrict__ e1,
                                                  const float* __restrict__ e2,
                                                  float* __restrict__ adp) {
  int r = blockIdx.x;
  int tid = threadIdx.x;
  __shared__ float red[256];
  __shared__ float e1row[16];
  if (tid < 10) e1row[tid] = e1[r * 10 + tid];
  __syncthreads();
  float z0, z1 = 0.f;
  {
    float acc = 0.f;
#pragma unroll
    for (int k = 0; k < 10; k++) acc += e1row[k] * e2[k * NN + tid];
    z0 = fmaxf(acc, 0.f);
  }
  bool has1 = (tid + 256) < NN;
  if (has1) {
    float acc = 0.f;
#pragma unroll
    for (int k = 0; k < 10; k++) acc += e1row[k] * e2[k * NN + tid + 256];
    z1 = fmaxf(acc, 0.f);
  }
  float mx = has1 ? fmaxf(z0, z1) : z0;
  red[tid] = mx;
  __syncthreads();
  for (int s = 128; s > 0; s >>= 1) {
    if (tid < s) red[tid] = fmaxf(red[tid], red[tid + s]);
    __syncthreads();
  }
  mx = red[0];
  __syncthreads();
  float ex0 = __expf(z0 - mx);
  float ex1 = has1 ? __expf(z1 - mx) : 0.f;
  red[tid] = ex0 + ex1;
  __syncthreads();
  for (int s = 128; s > 0; s >>= 1) {
    if (tid < s) red[tid] += red[tid + s];
    __syncthreads();
  }
  float inv = 1.f / red[0];
  adp[r * NN + tid] = ex0 * inv;
  if (has1) adp[r * NN + tid + 256] = ex1 * inv;
}

// ---------------------------------------------------------------------------
// xT[bc][t][n] = x[bc][n][t]  (coalesced reads for the fused layer-0 dconv)
__global__ __launch_bounds__(256) void xt_kernel(const float* __restrict__ x,
                                                 float* __restrict__ xT) {
  __shared__ float tile[32][33];
  int tx = threadIdx.x & 31, ty = threadIdx.x >> 5;
  int n0 = blockIdx.x * 32, t0 = blockIdx.y * 32, bc = blockIdx.z;
#pragma unroll
  for (int rr = 0; rr < 4; rr++) {
    int n = n0 + ty + rr * 8, t = t0 + tx;
    tile[ty + rr * 8][tx] = (n < NN) ? x[((size_t)bc * NN + n) * 256 + t] : 0.f;
  }
  __syncthreads();
#pragma unroll
  for (int rr = 0; rr < 4; rr++) {
    int t = t0 + ty + rr * 8, n = n0 + tx;
    if (n < NN) xT[((size_t)bc * 256 + t) * NN + n] = tile[tx][ty + rr * 8];
  }
}

// ---------------------------------------------------------------------------
// Transpose dconv weights [i][c][cp][tap] -> [i][cp][tap][c] so the dcm inner
// loop reads contiguous 64-float runs (batched s_load_dwordx16) instead of
// 128 scattered s_load_dword per cp iteration (round-10: VALUBusy 46%, the
// idle half = lgkm waits on constant-cache-thrashing scattered scalar loads).
__global__ __launch_bounds__(256) void wtr_kernel(const float* __restrict__ fw,
                                                  const float* __restrict__ gw,
                                                  float* __restrict__ fwT,
                                                  float* __restrict__ gwT) {
  int idx = blockIdx.x * 256 + threadIdx.x;  // 8*32*32*2 = 16384
  if (idx >= 16384) return;
  int c = idx & 31;
  int rest = idx >> 5;   // (i*32+cp)*2+tap
  int tap = rest & 1;
  int cpi = rest >> 1;   // i*32+cp
  int cp = cpi & 31, i = cpi >> 5;
  size_t src = (((size_t)(i * 32 + c) * 32 + cp) * 2) + tap;
  fwT[idx] = fw[src];
  gwT[idx] = gw[src];
}

// ---------------------------------------------------------------------------
// B^T as f16 hi/lo pair: hi[w][v]+lo[w][v] ~= src[v][w], 512x512 zero-padded.
__global__ __launch_bounds__(256) void bt_kernel(const float* __restrict__ src,
                                                 f16* __restrict__ hi,
                                                 f16* __restrict__ lo) {
  int idx = blockIdx.x * 256 + threadIdx.x;  // 512*512 total
  int w = idx >> 9, v = idx & 511;
  float x = (w < NN && v < NN) ? src[v * NN + w] : 0.f;
  f16 h = (f16)x;
  hi[idx] = h;
  lo[idx] = (f16)(x - (float)h);
}

// ---------------------------------------------------------------------------
// Squared-matrix B^T pair: dst[w][v] = (src @ src)[v][w].
__global__ __launch_bounds__(512) void sq_kernel(const float* __restrict__ srcA,
                                                 const float* __restrict__ srcB,
                                                 f16* __restrict__ hiA, f16* __restrict__ loA,
                                                 f16* __restrict__ hiB, f16* __restrict__ loB) {
  const float* src = blockIdx.y == 0 ? srcA : srcB;
  f16* hi = blockIdx.y == 0 ? hiA : hiB;
  f16* lo = blockIdx.y == 0 ? loA : loB;
  int v = blockIdx.x;   // 0..511
  int w = threadIdx.x;  // 0..511
  __shared__ float vrow[512];
  vrow[w] = (v < NN && w < NN) ? src[v * NN + w] : 0.f;
  __syncthreads();
  float acc = 0.f;
  if (v < NN && w < NN) {
#pragma unroll 4
    for (int u = 0; u < NN; u++) acc = fmaf(vrow[u], src[u * NN + w], acc);
  }
  size_t o = (size_t)w * 512 + v;
  f16 h = (f16)acc;
  hi[o] = h;
  lo[o] = (f16)(acc - (float)h);
}

// ---------------------------------------------------------------------------
// Zero pad columns [500,512) of the six f16 P arrays (ws re-poisoned 0xAA).
__global__ __launch_bounds__(256) void padzero_kernel(uint32_t* __restrict__ slab, int R) {
  int idx = blockIdx.x * 256 + threadIdx.x;
  int total = 6 * R * 6;
  if (idx >= total) return;
  int a = idx / (R * 6);
  int rem = idx - a * R * 6;
  int row = rem / 6;
  int q = rem - row * 6;
  slab[(size_t)a * R * 256 + (size_t)row * 256 + 250 + q] = 0u;
}

// ---------------------------------------------------------------------------
// Fused (start-conv) + dilated-conv + gating + GCN channel-mix. FG in registers.
// FUSED=true (layer 0): h comes from start-conv of xT on the fly.
// h residual stream fp32 (carries A^2-path terms up to ~1e3; f16 failed r8).
// fw/gw are the TRANSPOSED [cp][tap][c] weights (contiguous per-iteration).
// All register-array index loops fully unrolled (scratch-demotion hazard, r1).
template <bool FUSED>
__global__ __launch_bounds__(256) void dcm_kernel(
    const float* __restrict__ hprev, const float* __restrict__ xT,
    const float* __restrict__ sw, const float* __restrict__ sb,
    const float* __restrict__ fw, const float* __restrict__ fb,
    const float* __restrict__ gw, const float* __restrict__ gb,
    const float* __restrict__ cw, const float* __restrict__ cb,
    float* __restrict__ Hout,
    f16* __restrict__ P1a,
    f16* __restrict__ P2aH, f16* __restrict__ P2aL,
    f16* __restrict__ P1b,
    f16* __restrict__ P2bH, f16* __restrict__ P2bL,
    float* __restrict__ tapL,
    int Lp, int L, int b0) {
  int nc = blockIdx.x, j = blockIdx.y, bb = blockIdx.z;
  int n = nc * 256 + threadIdx.x;
  if (n >= NN) return;
  size_t base = ((size_t)(bb * 32) * Lp + 2 * j) * NN + n;
  size_t cs = (size_t)Lp * NN;
  float x00 = 0.f, x01 = 0.f, x10 = 0.f, x11 = 0.f;
  if (FUSED) {
    const float* xb = xT + (size_t)(b0 + bb) * 2 * 256 * NN;
    x00 = xb[(size_t)(2 * j) * NN + n];
    x01 = xb[(size_t)(2 * j + 1) * NN + n];
    x10 = xb[(size_t)(256 + 2 * j) * NN + n];
    x11 = xb[(size_t)(256 + 2 * j + 1) * NN + n];
  }
  float accf[32], accg[32];
#pragma unroll
  for (int c = 0; c < 32; c++) {
    accf[c] = fb[c];
    accg[c] = gb[c];
  }
#pragma unroll 2
  for (int cp = 0; cp < 32; cp++) {
    float v0, v1;
    if (FUSED) {
      float w0 = sw[cp * 2], w1 = sw[cp * 2 + 1], bc = sb[cp];
      v0 = fmaf(w0, x00, fmaf(w1, x10, bc));
      v1 = fmaf(w0, x01, fmaf(w1, x11, bc));
    } else {
      v0 = hprev[base + cp * cs];
      v1 = hprev[base + cp * cs + NN];
    }
    const float* fwp = fw + cp * 64;  // [cp][tap][c]: 64 contiguous floats
    const float* gwp = gw + cp * 64;
#pragma unroll
    for (int c = 0; c < 32; c++) {
      accf[c] = fmaf(fwp[c], v0, accf[c]);
      accf[c] = fmaf(fwp[32 + c], v1, accf[c]);
      accg[c] = fmaf(gwp[c], v0, accg[c]);
      accg[c] = fmaf(gwp[32 + c], v1, accg[c]);
    }
  }
  float FG[32];
#pragma unroll
  for (int c = 0; c < 32; c++) {
    float E = __expf(2.f * accf[c]);
    float th = 1.f - 2.f / (E + 1.f);          // tanh
    float sg = 1.f / (1.f + __expf(-accg[c])); // sigmoid
    FG[c] = th * sg;
  }
  if (j == L - 1) {
    size_t tbase = ((size_t)(b0 + bb) * 32) * NN + n;
#pragma unroll
    for (int c = 0; c < 32; c++) tapL[tbase + (size_t)c * NN] = FG[c];
  }
  if (Hout == nullptr) return;  // layer 8: only the skip tap survives
#pragma unroll 2
  for (int c = 0; c < 32; c++) {
    const float* wr = cw + c * 160;
    float h = cb[c], p1 = 0.f, p2 = 0.f, q1 = 0.f, q2 = 0.f;
#pragma unroll
    for (int cp = 0; cp < 32; cp++) {
      float f = FG[cp];
      h  = fmaf(wr[cp], f, h);
      p1 = fmaf(wr[32 + cp], f, p1);
      p2 = fmaf(wr[64 + cp], f, p2);
      q1 = fmaf(wr[96 + cp], f, q1);
      q2 = fmaf(wr[128 + cp], f, q2);
    }
    // residual = hprev[2j+1] (start-conv output for layer 0)
    if (FUSED) {
      h += fmaf(sw[c * 2], x01, fmaf(sw[c * 2 + 1], x11, sb[c]));
    } else {
      h += hprev[((size_t)(bb * 32 + c) * Lp + 2 * j + 1) * NN + n];
    }
    size_t mi = (size_t)(bb * 32 + c) * L + j;
    Hout[mi * NN + n] = h;
    size_t o = mi * KP + n;
    f16 t;
    P1a[o] = (f16)p1;
    t = (f16)p2; P2aH[o] = t; P2aL[o] = (f16)(p2 - (float)t);
    P1b[o] = (f16)q1;
    t = (f16)q2; P2bH[o] = t; P2bL[o] = (f16)(q2 - (float)t);
  }
}

// ---------------------------------------------------------------------------
// LDS-staged GCN node-mix GEMM (m97-style 2-barrier K-loop + register
// prefetch). Block 128m x 128n, 4 waves of 64x64 (4x4 subtiles of 16x16x32,
// acc=64 VGPR). LDS tiles 128x40 f16 (row pad 32->40: staging writes land
// 2-way bank-aliased = free, frag reads 2-way = free). Next 32-k strip is
// prefetched into 16 VGPRs right after the staging barrier so its L2 latency
// hides under the ds_read+MFMA phase. Pass loop fully unrolled -> all
// pointers static (SGPRs). Out = BN(Cin + sum_p A_p . B_p), fp32 in-place.
__global__ __launch_bounds__(256) void mfma_gcn(PassSet s,
    const float* __restrict__ Cin, float* __restrict__ Out, int M,
    const float* __restrict__ bng, const float* __restrict__ bnb, int lshift) {
  __shared__ f16 As[128 * 40];
  __shared__ f16 Bs[128 * 40];
  int tid = threadIdx.x;
  int wave = tid >> 6, lane = tid & 63;
  int wm = wave >> 1, wn = wave & 1;
  int m0 = blockIdx.x * 128;
  int n0 = blockIdx.y * 128;
  int lm = lane & 15, kq = lane >> 4;  // frag: row lm, k-quad kq (8 k)
  // staging: thread covers rows (tid>>2) and (tid>>2)+64, 16B chunk tid&3
  int srow = tid >> 2, sc = tid & 3;
  int ar0 = m0 + srow;      if (ar0 > M - 1) ar0 = M - 1;
  int ar1 = m0 + srow + 64; if (ar1 > M - 1) ar1 = M - 1;
  size_t ag0 = (size_t)ar0 * KP + sc * 8;
  size_t ag1 = (size_t)ar1 * KP + sc * 8;
  size_t bg0 = (size_t)(n0 + srow) * KP + sc * 8;
  size_t bg1 = (size_t)(n0 + srow + 64) * KP + sc * 8;
  int sl0 = srow * 40 + sc * 8;
  int sl1 = (srow + 64) * 40 + sc * 8;

  floatx4 acc[4][4];
#pragma unroll
  for (int i = 0; i < 4; i++)
#pragma unroll
    for (int j = 0; j < 4; j++) acc[i][j] = (floatx4){0.f, 0.f, 0.f, 0.f};

  float4 pa0, pa1, pb0, pb1;
  {
    const f16* Ap = s.A[0];
    const f16* Bp = s.B[0];
    pa0 = *(const float4*)(Ap + ag0);
    pa1 = *(const float4*)(Ap + ag1);
    pb0 = *(const float4*)(Bp + bg0);
    pb1 = *(const float4*)(Bp + bg1);
  }
#pragma unroll
  for (int p = 0; p < 10; p++) {
    const f16* __restrict__ Ap = s.A[p];
    const f16* __restrict__ Bp = s.B[p];
    const f16* __restrict__ Apn = s.A[p < 9 ? p + 1 : p];
    const f16* __restrict__ Bpn = s.B[p < 9 ? p + 1 : p];
    for (int k0 = 0; k0 < KP; k0 += 32) {
      __syncthreads();  // prior compute done reading LDS
      *(float4*)(As + sl0) = pa0;
      *(float4*)(As + sl1) = pa1;
      *(float4*)(Bs + sl0) = pb0;
      *(float4*)(Bs + sl1) = pb1;
      __syncthreads();  // staging visible
      {  // prefetch next strip; latency overlaps the compute below
        bool lastk = (k0 == KP - 32);
        const f16* An = lastk ? Apn : Ap;
        const f16* Bn = lastk ? Bpn : Bp;
        int kn = lastk ? 0 : k0 + 32;
        pa0 = *(const float4*)(An + ag0 + kn);
        pa1 = *(const float4*)(An + ag1 + kn);
        pb0 = *(const float4*)(Bn + bg0 + kn);
        pb1 = *(const float4*)(Bn + bg1 + kn);
      }
      half8 a[4];
#pragma unroll
      for (int i = 0; i < 4; i++)
        a[i] = *(const half8*)(As + (wm * 64 + i * 16 + lm) * 40 + kq * 8);
#pragma unroll
      for (int j = 0; j < 4; j++) {
        half8 b = *(const half8*)(Bs + (wn * 64 + j * 16 + lm) * 40 + kq * 8);
#pragma unroll
        for (int i = 0; i < 4; i++)
          acc[i][j] = __builtin_amdgcn_mfma_f32_16x16x32_f16(a[i], b, acc[i][j], 0, 0, 0);
      }
    }
  }
  // epilogue: C/D layout col = lane&15, row = (lane>>4)*4 + reg
  int cn = lane & 15, rq = lane >> 4;
  float rs = rsqrtf(1.f + 1e-5f);
#pragma unroll
  for (int i = 0; i < 4; i++) {
#pragma unroll
    for (int r = 0; r < 4; r++) {
      int row = m0 + wm * 64 + i * 16 + rq * 4 + r;
      if (row < M) {
        int c = (row >> lshift) & 31;  // m = (bb*32+c)*L + j
        float scale = bng[c] * rs;
        float bias = bnb[c];
#pragma unroll
        for (int j = 0; j < 4; j++) {
          int col = n0 + wn * 64 + j * 16 + cn;
          if (col < NN) {
            size_t o = (size_t)row * NN + col;
            Out[o] = (acc[i][j][r] + Cin[o]) * scale + bias;
          }
        }
      }
    }
  }
}

// ---------------------------------------------------------------------------
// skip -> relu -> end1 -> relu -> end2. One block per (b, 20 n-values).
#define NB 20
#define NBP 21
__global__ __launch_bounds__(256) void final_kernel(const float* __restrict__ tap,
    const float* __restrict__ skw, const float* __restrict__ skb,
    const float* __restrict__ e1w, const float* __restrict__ e1b,
    const float* __restrict__ e2w, const float* __restrict__ e2b,
    float* __restrict__ out) {
  __shared__ float tapS[256][NBP];
  __shared__ float skS[256][NBP];
  __shared__ float e1S[512][NBP];
  int tid = threadIdx.x;
  int b = blockIdx.y;
  int n0 = blockIdx.x * NB;
  {
    int i = tid >> 5, c = tid & 31;
    const float* tp = tap + (((size_t)i * 8 + b) * 32 + c) * NN + n0;
#pragma unroll
    for (int v = 0; v < NB; v++) tapS[tid][v] = tp[v];
  }
  __syncthreads();
  {
    float bsum = 0.f;
#pragma unroll
    for (int i2 = 0; i2 < 8; i2++) bsum += skb[i2 * 256 + tid];
    float acc[NB];
#pragma unroll
    for (int v = 0; v < NB; v++) acc[v] = bsum;
#pragma unroll
    for (int i2 = 0; i2 < 8; i2++) {
      const float* wr = skw + ((size_t)i2 * 256 + tid) * 32;
#pragma unroll
      for (int cp = 0; cp < 32; cp++) {
        float w = wr[cp];
#pragma unroll
        for (int v = 0; v < NB; v++) acc[v] = fmaf(w, tapS[i2 * 32 + cp][v], acc[v]);
      }
    }
#pragma unroll
    for (int v = 0; v < NB; v++) skS[tid][v] = fmaxf(acc[v], 0.f);
  }
  __syncthreads();
#pragma unroll
  for (int h = 0; h < 2; h++) {
    int k = tid + h * 256;
    float bv = e1b[k];
    float acc[NB];
#pragma unroll
    for (int v = 0; v < NB; v++) acc[v] = bv;
    const float* wr = e1w + (size_t)k * 256;
    for (int o = 0; o < 256; o++) {
      float w = wr[o];
#pragma unroll
      for (int v = 0; v < NB; v++) acc[v] = fmaf(w, skS[o][v], acc[v]);
    }
#pragma unroll
    for (int v = 0; v < NB; v++) e1S[k][v] = fmaxf(acc[v], 0.f);
  }
  __syncthreads();
  if (tid < 12 * NB) {
    int q = tid / NB, v = tid % NB;
    float acc = e2b[q];
    const float* wr = e2w + (size_t)q * 512;
#pragma unroll 8
    for (int k = 0; k < 512; k++) acc = fmaf(wr[k], e1S[k][v], acc);
    out[((size_t)b * 12 + q) * NN + n0 + v] = acc;
  }
}

// ---------------------------------------------------------------------------
extern "C" void kernel_launch(void* const* d_in, const int* in_sizes, int n_in,
                              void* d_out, int out_size, void* d_ws, size_t ws_size,
                              hipStream_t stream) {
  const float* x       = (const float*)d_in[0];
  const float* A0      = (const float*)d_in[1];
  const float* start_w = (const float*)d_in[2];
  const float* start_b = (const float*)d_in[3];
  const float* filt_w  = (const float*)d_in[4];
  const float* filt_b  = (const float*)d_in[5];
  const float* gate_w  = (const float*)d_in[6];
  const float* gate_b  = (const float*)d_in[7];
  const float* skip_w  = (const float*)d_in[8];
  const float* skip_b  = (const float*)d_in[9];
  const float* gcn_w   = (const float*)d_in[10];
  const float* gcn_b   = (const float*)d_in[11];
  const float* bn_g    = (const float*)d_in[12];
  const float* bn_b    = (const float*)d_in[13];
  const float* nv1     = (const float*)d_in[14];
  const float* nv2     = (const float*)d_in[15];
  const float* e1w     = (const float*)d_in[16];
  const float* e1b     = (const float*)d_in[17];
  const float* e2w     = (const float*)d_in[18];
  const float* e2b     = (const float*)d_in[19];
  float* out = (float*)d_out;

  char* ws = (char*)d_ws;
  size_t off = 0;
  auto alloc = [&](size_t bytes) -> void* {
    void* p = (void*)(ws + off);
    off += (bytes + 255) & ~(size_t)255;
    return p;
  };
  float* adp   = (float*)alloc((size_t)NN * NN * 4);
  float* tap   = (float*)alloc((size_t)8 * 8 * 32 * NN * 4);
  float* xT    = (float*)alloc((size_t)16 * 256 * NN * 4);  // [b*2+ch][t][n]
  float* fwT   = (float*)alloc((size_t)16384 * 4);  // dconv weights [i][cp][tap][c]
  float* gwT   = (float*)alloc((size_t)16384 * 4);
  f16*   A0tH  = (f16*)alloc((size_t)KP * KP * 2);
  f16*   A0tL  = (f16*)alloc((size_t)KP * KP * 2);
  f16*   adptH = (f16*)alloc((size_t)KP * KP * 2);
  f16*   adptL = (f16*)alloc((size_t)KP * KP * 2);
  f16*   Q0H   = (f16*)alloc((size_t)KP * KP * 2);   // (A0^2)^T pair
  f16*   Q0L   = (f16*)alloc((size_t)KP * KP * 2);
  f16*   QdH   = (f16*)alloc((size_t)KP * KP * 2);   // (adp^2)^T pair
  f16*   QdL   = (f16*)alloc((size_t)KP * KP * 2);
  size_t fixed = off;
  // per-batch: h128 (L<=128) + h64 (L<=64) fp32 + 6 f16 P arrays [32*128 x 512]
  const size_t perg = 8192000ull + 4096000ull + 6ull * 4194304ull;  // 37.45 MB
  int g = 8;
  while (g > 1 && fixed + (size_t)g * perg + 1048576 > ws_size) g >>= 1;
  float* h128 = (float*)alloc((size_t)g * 8192000ull);
  float* h64  = (float*)alloc((size_t)g * 4096000ull);
  f16* slab   = (f16*)alloc(6ull * g * 4194304ull);
  int R = g * 4096;  // rows per f16 array (layer-0 M)
  f16* P1a  = slab + 0ull * R * KP;
  f16* P2aH = slab + 1ull * R * KP;
  f16* P2aL = slab + 2ull * R * KP;
  f16* P1b  = slab + 3ull * R * KP;
  f16* P2bH = slab + 4ull * R * KP;
  f16* P2bL = slab + 5ull * R * KP;

  adp_kernel<<<NN, 256, 0, stream>>>(nv1, nv2, adp);
  xt_kernel<<<dim3(16, 8, 16), 256, 0, stream>>>(x, xT);
  wtr_kernel<<<64, 256, 0, stream>>>(filt_w, gate_w, fwT, gwT);
  bt_kernel<<<1024, 256, 0, stream>>>(A0, A0tH, A0tL);
  bt_kernel<<<1024, 256, 0, stream>>>(adp, adptH, adptL);
  sq_kernel<<<dim3(512, 2), 512, 0, stream>>>(A0, adp, Q0H, Q0L, QdH, QdL);
  padzero_kernel<<<(36 * R + 255) / 256, 256, 0, stream>>>((uint32_t*)slab, R);

  // out = H + P1a*A0 + P2a*A0^2 + P1b*adp + P2b*adp^2; P2 terms as hi/lo
  // pairs (3 passes, lo*lo dropped), P1 terms single-f16 (2 passes).
  // Flattened to 10 (A,B) passes (same arithmetic/order as round 9).
  PassSet ps{};
  {
    const f16* Alist[10] = {P1a, P1a, P2aH, P2aH, P2aL, P1b, P1b, P2bH, P2bH, P2bL};
    const f16* Blist[10] = {A0tH, A0tL, Q0H, Q0L, Q0H, adptH, adptL, QdH, QdL, QdH};
    for (int q = 0; q < 10; q++) { ps.A[q] = Alist[q]; ps.B[q] = Blist[q]; }
  }

  for (int b0 = 0; b0 < 8; b0 += g) {
    float* hprev = nullptr;
    int Lp = 256;
    for (int i = 0; i < 8; i++) {
      int L = Lp >> 1;  // 128,64,...,1
      if (i < 7) {
        float* hout = (i & 1) ? h64 : h128;
        if (i == 0) {
          dcm_kernel<true><<<dim3(2, L, g), 256, 0, stream>>>(
              nullptr, xT, start_w, start_b,
              fwT + i * 2048, filt_b + i * 32, gwT + i * 2048, gate_b + i * 32,
              gcn_w + i * 5120, gcn_b + i * 32, hout,
              P1a, P2aH, P2aL, P1b, P2bH, P2bL,
              tap + (size_t)i * 8 * 32 * NN, Lp, L, b0);
        } else {
          dcm_kernel<false><<<dim3(2, L, g), 256, 0, stream>>>(
              hprev, nullptr, nullptr, nullptr,
              fwT + i * 2048, filt_b + i * 32, gwT + i * 2048, gate_b + i * 32,
              gcn_w + i * 5120, gcn_b + i * 32, hout,
              P1a, P2aH, P2aL, P1b, P2bH, P2bL,
              tap + (size_t)i * 8 * 32 * NN, Lp, L, b0);
        }
        int M = g * 32 * L;
        int Mb = (M + 127) / 128;
        mfma_gcn<<<dim3(Mb, 4), 256, 0, stream>>>(ps, hout, hout, M,
                                                  bn_g + i * 32, bn_b + i * 32, 7 - i);
        hprev = hout;
        Lp = L;
      } else {
        // layer 8: only the skip tap survives
        dcm_kernel<false><<<dim3(2, 1, g), 256, 0, stream>>>(
            hprev, nullptr, nullptr, nullptr,
            fwT + i * 2048, filt_b + i * 32, gwT + i * 2048, gate_b + i * 32,
            gcn_w, gcn_b, nullptr,
            P1a, P2aH, P2aL, P1b, P2bH, P2bL,
            tap + (size_t)i * 8 * 32 * NN, Lp, 1, b0);
      }
    }
  }
  final_kernel<<<dim3(25, 8), 256, 0, stream>>>(tap, skip_w, skip_b, e1w, e1b, e2w, e2b, out);
}

// Round 12
// 2592.292 us; speedup vs baseline: 2.1078x; 1.4539x over previous
//
#include <hip/hip_runtime.h>
#include <cstdint>
#include <cstddef>

#define NN 500
#define KP 512   // node dim padded to 512 for f16 MFMA operands

typedef _Float16 f16;
typedef _Float16 half8 __attribute__((ext_vector_type(8)));
typedef float floatx4 __attribute__((ext_vector_type(4)));

// 10 flattened GEMM passes: acc += A[p] * B[p]^T.
struct PassSet {
  const f16* A[10];
  const f16* B[10];
};

// ---------------------------------------------------------------------------
// adp = softmax(relu(E1 @ E2), axis=1)
__global__ __launch_bounds__(256) void adp_kernel(const float* __restrict__ e1,
                                                  const float* __restrict__ e2,
                                                  float* __restrict__ adp) {
  int r = blockIdx.x;
  int tid = threadIdx.x;
  __shared__ float red[256];
  __shared__ float e1row[16];
  if (tid < 10) e1row[tid] = e1[r * 10 + tid];
  __syncthreads();
  float z0, z1 = 0.f;
  {
    float acc = 0.f;
#pragma unroll
    for (int k = 0; k < 10; k++) acc += e1row[k] * e2[k * NN + tid];
    z0 = fmaxf(acc, 0.f);
  }
  bool has1 = (tid + 256) < NN;
  if (has1) {
    float acc = 0.f;
#pragma unroll
    for (int k = 0; k < 10; k++) acc += e1row[k] * e2[k * NN + tid + 256];
    z1 = fmaxf(acc, 0.f);
  }
  float mx = has1 ? fmaxf(z0, z1) : z0;
  red[tid] = mx;
  __syncthreads();
  for (int s = 128; s > 0; s >>= 1) {
    if (tid < s) red[tid] = fmaxf(red[tid], red[tid + s]);
    __syncthreads();
  }
  mx = red[0];
  __syncthreads();
  float ex0 = __expf(z0 - mx);
  float ex1 = has1 ? __expf(z1 - mx) : 0.f;
  red[tid] = ex0 + ex1;
  __syncthreads();
  for (int s = 128; s > 0; s >>= 1) {
    if (tid < s) red[tid] += red[tid + s];
    __syncthreads();
  }
  float inv = 1.f / red[0];
  adp[r * NN + tid] = ex0 * inv;
  if (has1) adp[r * NN + tid + 256] = ex1 * inv;
}

// ---------------------------------------------------------------------------
// xT[bc][t][n] = x[bc][n][t]  (coalesced reads for the fused layer-0 dconv)
__global__ __launch_bounds__(256) void xt_kernel(const float* __restrict__ x,
                                                 float* __restrict__ xT) {
  __shared__ float tile[32][33];
  int tx = threadIdx.x & 31, ty = threadIdx.x >> 5;
  int n0 = blockIdx.x * 32, t0 = blockIdx.y * 32, bc = blockIdx.z;
#pragma unroll
  for (int rr = 0; rr < 4; rr++) {
    int n = n0 + ty + rr * 8, t = t0 + tx;
    tile[ty + rr * 8][tx] = (n < NN) ? x[((size_t)bc * NN + n) * 256 + t] : 0.f;
  }
  __syncthreads();
#pragma unroll
  for (int rr = 0; rr < 4; rr++) {
    int t = t0 + ty + rr * 8, n = n0 + tx;
    if (n < NN) xT[((size_t)bc * 256 + t) * NN + n] = tile[tx][ty + rr * 8];
  }
}

// ---------------------------------------------------------------------------
// Transpose dconv weights [i][c][cp][tap] -> [i][cp][tap][c] (contiguous runs).
__global__ __launch_bounds__(256) void wtr_kernel(const float* __restrict__ fw,
                                                  const float* __restrict__ gw,
                                                  float* __restrict__ fwT,
                                                  float* __restrict__ gwT) {
  int idx = blockIdx.x * 256 + threadIdx.x;  // 8*32*32*2 = 16384
  if (idx >= 16384) return;
  int c = idx & 31;
  int rest = idx >> 5;   // (i*32+cp)*2+tap
  int tap = rest & 1;
  int cpi = rest >> 1;   // i*32+cp
  int cp = cpi & 31, i = cpi >> 5;
  size_t src = (((size_t)(i * 32 + c) * 32 + cp) * 2) + tap;
  fwT[idx] = fw[src];
  gwT[idx] = gw[src];
}

// ---------------------------------------------------------------------------
// B^T as f16 hi/lo pair: hi[w][v]+lo[w][v] ~= src[v][w], 512x512 zero-padded.
__global__ __launch_bounds__(256) void bt_kernel(const float* __restrict__ src,
                                                 f16* __restrict__ hi,
                                                 f16* __restrict__ lo) {
  int idx = blockIdx.x * 256 + threadIdx.x;  // 512*512 total
  int w = idx >> 9, v = idx & 511;
  float x = (w < NN && v < NN) ? src[v * NN + w] : 0.f;
  f16 h = (f16)x;
  hi[idx] = h;
  lo[idx] = (f16)(x - (float)h);
}

// ---------------------------------------------------------------------------
// Squared-matrix B^T pair: dst[w][v] = (src @ src)[v][w].
__global__ __launch_bounds__(512) void sq_kernel(const float* __restrict__ srcA,
                                                 const float* __restrict__ srcB,
                                                 f16* __restrict__ hiA, f16* __restrict__ loA,
                                                 f16* __restrict__ hiB, f16* __restrict__ loB) {
  const float* src = blockIdx.y == 0 ? srcA : srcB;
  f16* hi = blockIdx.y == 0 ? hiA : hiB;
  f16* lo = blockIdx.y == 0 ? loA : loB;
  int v = blockIdx.x;   // 0..511
  int w = threadIdx.x;  // 0..511
  __shared__ float vrow[512];
  vrow[w] = (v < NN && w < NN) ? src[v * NN + w] : 0.f;
  __syncthreads();
  float acc = 0.f;
  if (v < NN && w < NN) {
#pragma unroll 4
    for (int u = 0; u < NN; u++) acc = fmaf(vrow[u], src[u * NN + w], acc);
  }
  size_t o = (size_t)w * 512 + v;
  f16 h = (f16)acc;
  hi[o] = h;
  lo[o] = (f16)(acc - (float)h);
}

// ---------------------------------------------------------------------------
// Zero pad columns [500,512) of the six f16 P arrays (ws re-poisoned 0xAA).
__global__ __launch_bounds__(256) void padzero_kernel(uint32_t* __restrict__ slab, int R) {
  int idx = blockIdx.x * 256 + threadIdx.x;
  int total = 6 * R * 6;
  if (idx >= total) return;
  int a = idx / (R * 6);
  int rem = idx - a * R * 6;
  int row = rem / 6;
  int q = rem - row * 6;
  slab[(size_t)a * R * 256 + (size_t)row * 256 + 250 + q] = 0u;
}

// ---------------------------------------------------------------------------
// Fused (start-conv) + dilated-conv + gating + GCN channel-mix. FG in registers.
// FUSED=true (layer 0): h comes from start-conv of xT on the fly.
// h residual stream fp32 (carries A^2-path terms up to ~1e3; f16 failed r8).
// fw/gw are the TRANSPOSED [cp][tap][c] weights (contiguous per-iteration).
// All register-array index loops fully unrolled (scratch-demotion hazard, r1).
// b0 = GLOBAL batch index of this launch's bb=0 (bb-chunked launches).
template <bool FUSED>
__global__ __launch_bounds__(256) void dcm_kernel(
    const float* __restrict__ hprev, const float* __restrict__ xT,
    const float* __restrict__ sw, const float* __restrict__ sb,
    const float* __restrict__ fw, const float* __restrict__ fb,
    const float* __restrict__ gw, const float* __restrict__ gb,
    const float* __restrict__ cw, const float* __restrict__ cb,
    float* __restrict__ Hout,
    f16* __restrict__ P1a,
    f16* __restrict__ P2aH, f16* __restrict__ P2aL,
    f16* __restrict__ P1b,
    f16* __restrict__ P2bH, f16* __restrict__ P2bL,
    float* __restrict__ tapL,
    int Lp, int L, int b0) {
  int nc = blockIdx.x, j = blockIdx.y, bb = blockIdx.z;
  int n = nc * 256 + threadIdx.x;
  if (n >= NN) return;
  size_t base = ((size_t)(bb * 32) * Lp + 2 * j) * NN + n;
  size_t cs = (size_t)Lp * NN;
  float x00 = 0.f, x01 = 0.f, x10 = 0.f, x11 = 0.f;
  if (FUSED) {
    const float* xb = xT + (size_t)(b0 + bb) * 2 * 256 * NN;
    x00 = xb[(size_t)(2 * j) * NN + n];
    x01 = xb[(size_t)(2 * j + 1) * NN + n];
    x10 = xb[(size_t)(256 + 2 * j) * NN + n];
    x11 = xb[(size_t)(256 + 2 * j + 1) * NN + n];
  }
  float accf[32], accg[32];
#pragma unroll
  for (int c = 0; c < 32; c++) {
    accf[c] = fb[c];
    accg[c] = gb[c];
  }
#pragma unroll 2
  for (int cp = 0; cp < 32; cp++) {
    float v0, v1;
    if (FUSED) {
      float w0 = sw[cp * 2], w1 = sw[cp * 2 + 1], bc = sb[cp];
      v0 = fmaf(w0, x00, fmaf(w1, x10, bc));
      v1 = fmaf(w0, x01, fmaf(w1, x11, bc));
    } else {
      v0 = hprev[base + cp * cs];
      v1 = hprev[base + cp * cs + NN];
    }
    const float* fwp = fw + cp * 64;  // [cp][tap][c]: 64 contiguous floats
    const float* gwp = gw + cp * 64;
#pragma unroll
    for (int c = 0; c < 32; c++) {
      accf[c] = fmaf(fwp[c], v0, accf[c]);
      accf[c] = fmaf(fwp[32 + c], v1, accf[c]);
      accg[c] = fmaf(gwp[c], v0, accg[c]);
      accg[c] = fmaf(gwp[32 + c], v1, accg[c]);
    }
  }
  float FG[32];
#pragma unroll
  for (int c = 0; c < 32; c++) {
    float E = __expf(2.f * accf[c]);
    float th = 1.f - 2.f / (E + 1.f);          // tanh
    float sg = 1.f / (1.f + __expf(-accg[c])); // sigmoid
    FG[c] = th * sg;
  }
  if (j == L - 1) {
    size_t tbase = ((size_t)(b0 + bb) * 32) * NN + n;
#pragma unroll
    for (int c = 0; c < 32; c++) tapL[tbase + (size_t)c * NN] = FG[c];
  }
  if (Hout == nullptr) return;  // layer 8: only the skip tap survives
#pragma unroll 2
  for (int c = 0; c < 32; c++) {
    const float* wr = cw + c * 160;
    float h = cb[c], p1 = 0.f, p2 = 0.f, q1 = 0.f, q2 = 0.f;
#pragma unroll
    for (int cp = 0; cp < 32; cp++) {
      float f = FG[cp];
      h  = fmaf(wr[cp], f, h);
      p1 = fmaf(wr[32 + cp], f, p1);
      p2 = fmaf(wr[64 + cp], f, p2);
      q1 = fmaf(wr[96 + cp], f, q1);
      q2 = fmaf(wr[128 + cp], f, q2);
    }
    // residual = hprev[2j+1] (start-conv output for layer 0)
    if (FUSED) {
      h += fmaf(sw[c * 2], x01, fmaf(sw[c * 2 + 1], x11, sb[c]));
    } else {
      h += hprev[((size_t)(bb * 32 + c) * Lp + 2 * j + 1) * NN + n];
    }
    size_t mi = (size_t)(bb * 32 + c) * L + j;
    Hout[mi * NN + n] = h;
    size_t o = mi * KP + n;
    f16 t;
    P1a[o] = (f16)p1;
    t = (f16)p2; P2aH[o] = t; P2aL[o] = (f16)(p2 - (float)t);
    P1b[o] = (f16)q1;
    t = (f16)q2; P2bH[o] = t; P2bL[o] = (f16)(q2 - (float)t);
  }
}

// ---------------------------------------------------------------------------
// LDS-staged GCN node-mix GEMM (m97-style 2-barrier K-loop + register
// prefetch). Block 128m x 128n, 4 waves of 64x64 (4x4 subtiles of 16x16x32,
// acc=64 VGPR). LDS tiles 128x40 f16 (row pad 32->40: 2-way bank aliasing =
// free). Next 32-k strip prefetched into 16 VGPRs right after the staging
// barrier. Pass loop fully unrolled. Out = BN(Cin + sum_p A_p.B_p), in-place.
__global__ __launch_bounds__(256) void mfma_gcn(PassSet s,
    const float* __restrict__ Cin, float* __restrict__ Out, int M,
    const float* __restrict__ bng, const float* __restrict__ bnb, int lshift) {
  __shared__ f16 As[128 * 40];
  __shared__ f16 Bs[128 * 40];
  int tid = threadIdx.x;
  int wave = tid >> 6, lane = tid & 63;
  int wm = wave >> 1, wn = wave & 1;
  int m0 = blockIdx.x * 128;
  int n0 = blockIdx.y * 128;
  int lm = lane & 15, kq = lane >> 4;  // frag: row lm, k-quad kq (8 k)
  // staging: thread covers rows (tid>>2) and (tid>>2)+64, 16B chunk tid&3
  int srow = tid >> 2, sc = tid & 3;
  int ar0 = m0 + srow;      if (ar0 > M - 1) ar0 = M - 1;
  int ar1 = m0 + srow + 64; if (ar1 > M - 1) ar1 = M - 1;
  size_t ag0 = (size_t)ar0 * KP + sc * 8;
  size_t ag1 = (size_t)ar1 * KP + sc * 8;
  size_t bg0 = (size_t)(n0 + srow) * KP + sc * 8;
  size_t bg1 = (size_t)(n0 + srow + 64) * KP + sc * 8;
  int sl0 = srow * 40 + sc * 8;
  int sl1 = (srow + 64) * 40 + sc * 8;

  floatx4 acc[4][4];
#pragma unroll
  for (int i = 0; i < 4; i++)
#pragma unroll
    for (int j = 0; j < 4; j++) acc[i][j] = (floatx4){0.f, 0.f, 0.f, 0.f};

  float4 pa0, pa1, pb0, pb1;
  {
    const f16* Ap = s.A[0];
    const f16* Bp = s.B[0];
    pa0 = *(const float4*)(Ap + ag0);
    pa1 = *(const float4*)(Ap + ag1);
    pb0 = *(const float4*)(Bp + bg0);
    pb1 = *(const float4*)(Bp + bg1);
  }
#pragma unroll
  for (int p = 0; p < 10; p++) {
    const f16* __restrict__ Ap = s.A[p];
    const f16* __restrict__ Bp = s.B[p];
    const f16* __restrict__ Apn = s.A[p < 9 ? p + 1 : p];
    const f16* __restrict__ Bpn = s.B[p < 9 ? p + 1 : p];
    for (int k0 = 0; k0 < KP; k0 += 32) {
      __syncthreads();  // prior compute done reading LDS
      *(float4*)(As + sl0) = pa0;
      *(float4*)(As + sl1) = pa1;
      *(float4*)(Bs + sl0) = pb0;
      *(float4*)(Bs + sl1) = pb1;
      __syncthreads();  // staging visible
      {  // prefetch next strip; latency overlaps the compute below
        bool lastk = (k0 == KP - 32);
        const f16* An = lastk ? Apn : Ap;
        const f16* Bn = lastk ? Bpn : Bp;
        int kn = lastk ? 0 : k0 + 32;
        pa0 = *(const float4*)(An + ag0 + kn);
        pa1 = *(const float4*)(An + ag1 + kn);
        pb0 = *(const float4*)(Bn + bg0 + kn);
        pb1 = *(const float4*)(Bn + bg1 + kn);
      }
      half8 a[4];
#pragma unroll
      for (int i = 0; i < 4; i++)
        a[i] = *(const half8*)(As + (wm * 64 + i * 16 + lm) * 40 + kq * 8);
#pragma unroll
      for (int j = 0; j < 4; j++) {
        half8 b = *(const half8*)(Bs + (wn * 64 + j * 16 + lm) * 40 + kq * 8);
#pragma unroll
        for (int i = 0; i < 4; i++)
          acc[i][j] = __builtin_amdgcn_mfma_f32_16x16x32_f16(a[i], b, acc[i][j], 0, 0, 0);
      }
    }
  }
  // epilogue: C/D layout col = lane&15, row = (lane>>4)*4 + reg
  int cn = lane & 15, rq = lane >> 4;
  float rs = rsqrtf(1.f + 1e-5f);
#pragma unroll
  for (int i = 0; i < 4; i++) {
#pragma unroll
    for (int r = 0; r < 4; r++) {
      int row = m0 + wm * 64 + i * 16 + rq * 4 + r;
      if (row < M) {
        int c = (row >> lshift) & 31;  // m = (bb*32+c)*L + j
        float scale = bng[c] * rs;
        float bias = bnb[c];
#pragma unroll
        for (int j = 0; j < 4; j++) {
          int col = n0 + wn * 64 + j * 16 + cn;
          if (col < NN) {
            size_t o = (size_t)row * NN + col;
            Out[o] = (acc[i][j][r] + Cin[o]) * scale + bias;
          }
        }
      }
    }
  }
}

// ---------------------------------------------------------------------------
// skip -> relu -> end1 -> relu -> end2. One block per (b, 20 n-values).
#define NB 20
#define NBP 21
__global__ __launch_bounds__(256) void final_kernel(const float* __restrict__ tap,
    const float* __restrict__ skw, const float* __restrict__ skb,
    const float* __restrict__ e1w, const float* __restrict__ e1b,
    const float* __restrict__ e2w, const float* __restrict__ e2b,
    float* __restrict__ out) {
  __shared__ float tapS[256][NBP];
  __shared__ float skS[256][NBP];
  __shared__ float e1S[512][NBP];
  int tid = threadIdx.x;
  int b = blockIdx.y;
  int n0 = blockIdx.x * NB;
  {
    int i = tid >> 5, c = tid & 31;
    const float* tp = tap + (((size_t)i * 8 + b) * 32 + c) * NN + n0;
#pragma unroll
    for (int v = 0; v < NB; v++) tapS[tid][v] = tp[v];
  }
  __syncthreads();
  {
    float bsum = 0.f;
#pragma unroll
    for (int i2 = 0; i2 < 8; i2++) bsum += skb[i2 * 256 + tid];
    float acc[NB];
#pragma unroll
    for (int v = 0; v < NB; v++) acc[v] = bsum;
#pragma unroll
    for (int i2 = 0; i2 < 8; i2++) {
      const float* wr = skw + ((size_t)i2 * 256 + tid) * 32;
#pragma unroll
      for (int cp = 0; cp < 32; cp++) {
        float w = wr[cp];
#pragma unroll
        for (int v = 0; v < NB; v++) acc[v] = fmaf(w, tapS[i2 * 32 + cp][v], acc[v]);
      }
    }
#pragma unroll
    for (int v = 0; v < NB; v++) skS[tid][v] = fmaxf(acc[v], 0.f);
  }
  __syncthreads();
#pragma unroll
  for (int h = 0; h < 2; h++) {
    int k = tid + h * 256;
    float bv = e1b[k];
    float acc[NB];
#pragma unroll
    for (int v = 0; v < NB; v++) acc[v] = bv;
    const float* wr = e1w + (size_t)k * 256;
    for (int o = 0; o < 256; o++) {
      float w = wr[o];
#pragma unroll
      for (int v = 0; v < NB; v++) acc[v] = fmaf(w, skS[o][v], acc[v]);
    }
#pragma unroll
    for (int v = 0; v < NB; v++) e1S[k][v] = fmaxf(acc[v], 0.f);
  }
  __syncthreads();
  if (tid < 12 * NB) {
    int q = tid / NB, v = tid % NB;
    float acc = e2b[q];
    const float* wr = e2w + (size_t)q * 512;
#pragma unroll 8
    for (int k = 0; k < 512; k++) acc = fmaf(wr[k], e1S[k][v], acc);
    out[((size_t)b * 12 + q) * NN + n0 + v] = acc;
  }
}

// ---------------------------------------------------------------------------
extern "C" void kernel_launch(void* const* d_in, const int* in_sizes, int n_in,
                              void* d_out, int out_size, void* d_ws, size_t ws_size,
                              hipStream_t stream) {
  const float* x       = (const float*)d_in[0];
  const float* A0      = (const float*)d_in[1];
  const float* start_w = (const float*)d_in[2];
  const float* start_b = (const float*)d_in[3];
  const float* filt_w  = (const float*)d_in[4];
  const float* filt_b  = (const float*)d_in[5];
  const float* gate_w  = (const float*)d_in[6];
  const float* gate_b  = (const float*)d_in[7];
  const float* skip_w  = (const float*)d_in[8];
  const float* skip_b  = (const float*)d_in[9];
  const float* gcn_w   = (const float*)d_in[10];
  const float* gcn_b   = (const float*)d_in[11];
  const float* bn_g    = (const float*)d_in[12];
  const float* bn_b    = (const float*)d_in[13];
  const float* nv1     = (const float*)d_in[14];
  const float* nv2     = (const float*)d_in[15];
  const float* e1w     = (const float*)d_in[16];
  const float* e1b     = (const float*)d_in[17];
  const float* e2w     = (const float*)d_in[18];
  const float* e2b     = (const float*)d_in[19];
  float* out = (float*)d_out;

  char* ws = (char*)d_ws;
  size_t off = 0;
  auto alloc = [&](size_t bytes) -> void* {
    void* p = (void*)(ws + off);
    off += (bytes + 255) & ~(size_t)255;
    return p;
  };
  float* adp   = (float*)alloc((size_t)NN * NN * 4);
  float* tap   = (float*)alloc((size_t)8 * 8 * 32 * NN * 4);
  float* xT    = (float*)alloc((size_t)16 * 256 * NN * 4);  // [b*2+ch][t][n]
  float* fwT   = (float*)alloc((size_t)16384 * 4);  // dconv weights [i][cp][tap][c]
  float* gwT   = (float*)alloc((size_t)16384 * 4);
  f16*   A0tH  = (f16*)alloc((size_t)KP * KP * 2);
  f16*   A0tL  = (f16*)alloc((size_t)KP * KP * 2);
  f16*   adptH = (f16*)alloc((size_t)KP * KP * 2);
  f16*   adptL = (f16*)alloc((size_t)KP * KP * 2);
  f16*   Q0H   = (f16*)alloc((size_t)KP * KP * 2);   // (A0^2)^T pair
  f16*   Q0L   = (f16*)alloc((size_t)KP * KP * 2);
  f16*   QdH   = (f16*)alloc((size_t)KP * KP * 2);   // (adp^2)^T pair
  f16*   QdL   = (f16*)alloc((size_t)KP * KP * 2);
  size_t fixed = off;

  // Workspace ladder: pick batch-group g and rows-per-batch slab capacity rpb.
  // Layer i (rows/batch = 32*L_i) runs in nCh = ceil(32*L_i/rpb) bb-chunks
  // (pointer offsets only, bit-identical math). Worst-case config (g=8,
  // rpb=512) needs ~141 MB; r7-r11's g=4 proves ws >= ~168 MB, so g=8 always.
  int g = 1, rpb = 512;
  {
    const int gcand[4] = {8, 4, 2, 1};
    const int rcand[4] = {4096, 2048, 1024, 512};
    bool found = false;
    for (int gi = 0; gi < 4 && !found; gi++) {
      for (int ri = 0; ri < 4 && !found; ri++) {
        int gg = gcand[gi], rr = rcand[ri];
        if (4096 / rr > gg) continue;  // layer-0 chunk count must be <= g
        size_t need = fixed + (size_t)gg * 12288000ull +
                      6ull * gg * rr * KP * 2 + (1u << 20);
        if (need <= ws_size) { g = gg; rpb = rr; found = true; }
      }
    }
  }
  float* h128 = (float*)alloc((size_t)g * 8192000ull);
  float* h64  = (float*)alloc((size_t)g * 4096000ull);
  int R = g * rpb;  // slab rows per f16 array
  f16* slab   = (f16*)alloc(6ull * R * KP * 2);
  f16* P1a  = slab + 0ull * R * KP;
  f16* P2aH = slab + 1ull * R * KP;
  f16* P2aL = slab + 2ull * R * KP;
  f16* P1b  = slab + 3ull * R * KP;
  f16* P2bH = slab + 4ull * R * KP;
  f16* P2bL = slab + 5ull * R * KP;

  adp_kernel<<<NN, 256, 0, stream>>>(nv1, nv2, adp);
  xt_kernel<<<dim3(16, 8, 16), 256, 0, stream>>>(x, xT);
  wtr_kernel<<<64, 256, 0, stream>>>(filt_w, gate_w, fwT, gwT);
  bt_kernel<<<1024, 256, 0, stream>>>(A0, A0tH, A0tL);
  bt_kernel<<<1024, 256, 0, stream>>>(adp, adptH, adptL);
  sq_kernel<<<dim3(512, 2), 512, 0, stream>>>(A0, adp, Q0H, Q0L, QdH, QdL);
  padzero_kernel<<<(36 * R + 255) / 256, 256, 0, stream>>>((uint32_t*)slab, R);

  // out = H + P1a*A0 + P2a*A0^2 + P1b*adp + P2b*adp^2; P2 terms as hi/lo
  // pairs (3 passes, lo*lo dropped), P1 terms single-f16 (2 passes).
  PassSet ps{};
  {
    const f16* Alist[10] = {P1a, P1a, P2aH, P2aH, P2aL, P1b, P1b, P2bH, P2bH, P2bL};
    const f16* Blist[10] = {A0tH, A0tL, Q0H, Q0L, Q0H, adptH, adptL, QdH, QdL, QdH};
    for (int q = 0; q < 10; q++) { ps.A[q] = Alist[q]; ps.B[q] = Blist[q]; }
  }

  for (int b0 = 0; b0 < 8; b0 += g) {
    float* hprev = nullptr;
    int Lp = 256;
    for (int i = 0; i < 8; i++) {
      int L = Lp >> 1;  // 128,64,...,1
      if (i < 7) {
        float* hout = (i & 1) ? h64 : h128;
        int rows = 32 * L;                       // per batch element
        int nCh = (rows + rpb - 1) / rpb;        // bb-chunks (<= g, power of 2)
        if (nCh < 1) nCh = 1;
        int bbw = g / nCh;
        for (int ch = 0; ch < nCh; ch++) {
          int bb0 = ch * bbw;
          const float* hprev_c = hprev ? hprev + (size_t)bb0 * 32 * Lp * NN : nullptr;
          float* hout_c = hout + (size_t)bb0 * 32 * L * NN;
          if (i == 0) {
            dcm_kernel<true><<<dim3(2, L, bbw), 256, 0, stream>>>(
                nullptr, xT, start_w, start_b,
                fwT + i * 2048, filt_b + i * 32, gwT + i * 2048, gate_b + i * 32,
                gcn_w + i * 5120, gcn_b + i * 32, hout_c,
                P1a, P2aH, P2aL, P1b, P2bH, P2bL,
                tap + (size_t)i * 8 * 32 * NN, Lp, L, b0 + bb0);
          } else {
            dcm_kernel<false><<<dim3(2, L, bbw), 256, 0, stream>>>(
                hprev_c, nullptr, nullptr, nullptr,
                fwT + i * 2048, filt_b + i * 32, gwT + i * 2048, gate_b + i * 32,
                gcn_w + i * 5120, gcn_b + i * 32, hout_c,
                P1a, P2aH, P2aL, P1b, P2bH, P2bL,
                tap + (size_t)i * 8 * 32 * NN, Lp, L, b0 + bb0);
          }
          int M = bbw * 32 * L;
          int Mb = (M + 127) / 128;
          mfma_gcn<<<dim3(Mb, 4), 256, 0, stream>>>(ps, hout_c, hout_c, M,
                                                    bn_g + i * 32, bn_b + i * 32, 7 - i);
        }
        hprev = hout;
        Lp = L;
      } else {
        // layer 8: only the skip tap survives
        dcm_kernel<false><<<dim3(2, 1, g), 256, 0, stream>>>(
            hprev, nullptr, nullptr, nullptr,
            fwT + i * 2048, filt_b + i * 32, gwT + i * 2048, gate_b + i * 32,
            gcn_w, gcn_b, nullptr,
            P1a, P2aH, P2aL, P1b, P2bH, P2bL,
            tap + (size_t)i * 8 * 32 * NN, Lp, 1, b0);
      }
    }
  }
  final_kernel<<<dim3(25, 8), 256, 0, stream>>>(tap, skip_w, skip_b, e1w, e1b, e2w, e2b, out);
}

// Round 13
// 2346.343 us; speedup vs baseline: 2.3288x; 1.1048x over previous
//
#include <hip/hip_runtime.h>
#include <cstdint>
#include <cstddef>

#define NN 500
#define KP 512   // node dim padded to 512 for f16 MFMA operands

typedef _Float16 f16;
typedef _Float16 half8 __attribute__((ext_vector_type(8)));
typedef float floatx4 __attribute__((ext_vector_type(4)));

// 10 flattened GEMM passes: acc += A[p] * B[p]^T.
struct PassSet {
  const f16* A[10];
  const f16* B[10];
};

// ---------------------------------------------------------------------------
// adp = softmax(relu(E1 @ E2), axis=1)
__global__ __launch_bounds__(256) void adp_kernel(const float* __restrict__ e1,
                                                  const float* __restrict__ e2,
                                                  float* __restrict__ adp) {
  int r = blockIdx.x;
  int tid = threadIdx.x;
  __shared__ float red[256];
  __shared__ float e1row[16];
  if (tid < 10) e1row[tid] = e1[r * 10 + tid];
  __syncthreads();
  float z0, z1 = 0.f;
  {
    float acc = 0.f;
#pragma unroll
    for (int k = 0; k < 10; k++) acc += e1row[k] * e2[k * NN + tid];
    z0 = fmaxf(acc, 0.f);
  }
  bool has1 = (tid + 256) < NN;
  if (has1) {
    float acc = 0.f;
#pragma unroll
    for (int k = 0; k < 10; k++) acc += e1row[k] * e2[k * NN + tid + 256];
    z1 = fmaxf(acc, 0.f);
  }
  float mx = has1 ? fmaxf(z0, z1) : z0;
  red[tid] = mx;
  __syncthreads();
  for (int s = 128; s > 0; s >>= 1) {
    if (tid < s) red[tid] = fmaxf(red[tid], red[tid + s]);
    __syncthreads();
  }
  mx = red[0];
  __syncthreads();
  float ex0 = __expf(z0 - mx);
  float ex1 = has1 ? __expf(z1 - mx) : 0.f;
  red[tid] = ex0 + ex1;
  __syncthreads();
  for (int s = 128; s > 0; s >>= 1) {
    if (tid < s) red[tid] += red[tid + s];
    __syncthreads();
  }
  float inv = 1.f / red[0];
  adp[r * NN + tid] = ex0 * inv;
  if (has1) adp[r * NN + tid + 256] = ex1 * inv;
}

// ---------------------------------------------------------------------------
// xT[bc][t][n] = x[bc][n][t]  (coalesced reads for the fused layer-0 dconv)
__global__ __launch_bounds__(256) void xt_kernel(const float* __restrict__ x,
                                                 float* __restrict__ xT) {
  __shared__ float tile[32][33];
  int tx = threadIdx.x & 31, ty = threadIdx.x >> 5;
  int n0 = blockIdx.x * 32, t0 = blockIdx.y * 32, bc = blockIdx.z;
#pragma unroll
  for (int rr = 0; rr < 4; rr++) {
    int n = n0 + ty + rr * 8, t = t0 + tx;
    tile[ty + rr * 8][tx] = (n < NN) ? x[((size_t)bc * NN + n) * 256 + t] : 0.f;
  }
  __syncthreads();
#pragma unroll
  for (int rr = 0; rr < 4; rr++) {
    int t = t0 + ty + rr * 8, n = n0 + tx;
    if (n < NN) xT[((size_t)bc * 256 + t) * NN + n] = tile[tx][ty + rr * 8];
  }
}

// ---------------------------------------------------------------------------
// Transpose dconv weights [i][c][cp][tap] -> [i][cp][tap][c] (contiguous runs).
__global__ __launch_bounds__(256) void wtr_kernel(const float* __restrict__ fw,
                                                  const float* __restrict__ gw,
                                                  float* __restrict__ fwT,
                                                  float* __restrict__ gwT) {
  int idx = blockIdx.x * 256 + threadIdx.x;  // 8*32*32*2 = 16384
  if (idx >= 16384) return;
  int c = idx & 31;
  int rest = idx >> 5;   // (i*32+cp)*2+tap
  int tap = rest & 1;
  int cpi = rest >> 1;   // i*32+cp
  int cp = cpi & 31, i = cpi >> 5;
  size_t src = (((size_t)(i * 32 + c) * 32 + cp) * 2) + tap;
  fwT[idx] = fw[src];
  gwT[idx] = gw[src];
}

// ---------------------------------------------------------------------------
// B^T as f16 hi/lo pair: hi[w][v]+lo[w][v] ~= src[v][w], 512x512 zero-padded.
__global__ __launch_bounds__(256) void bt_kernel(const float* __restrict__ src,
                                                 f16* __restrict__ hi,
                                                 f16* __restrict__ lo) {
  int idx = blockIdx.x * 256 + threadIdx.x;  // 512*512 total
  int w = idx >> 9, v = idx & 511;
  float x = (w < NN && v < NN) ? src[v * NN + w] : 0.f;
  f16 h = (f16)x;
  hi[idx] = h;
  lo[idx] = (f16)(x - (float)h);
}

// ---------------------------------------------------------------------------
// Squared-matrix B^T pair: dst[w][v] = (src @ src)[v][w].
__global__ __launch_bounds__(512) void sq_kernel(const float* __restrict__ srcA,
                                                 const float* __restrict__ srcB,
                                                 f16* __restrict__ hiA, f16* __restrict__ loA,
                                                 f16* __restrict__ hiB, f16* __restrict__ loB) {
  const float* src = blockIdx.y == 0 ? srcA : srcB;
  f16* hi = blockIdx.y == 0 ? hiA : hiB;
  f16* lo = blockIdx.y == 0 ? loA : loB;
  int v = blockIdx.x;   // 0..511
  int w = threadIdx.x;  // 0..511
  __shared__ float vrow[512];
  vrow[w] = (v < NN && w < NN) ? src[v * NN + w] : 0.f;
  __syncthreads();
  float acc = 0.f;
  if (v < NN && w < NN) {
#pragma unroll 4
    for (int u = 0; u < NN; u++) acc = fmaf(vrow[u], src[u * NN + w], acc);
  }
  size_t o = (size_t)w * 512 + v;
  f16 h = (f16)acc;
  hi[o] = h;
  lo[o] = (f16)(acc - (float)h);
}

// ---------------------------------------------------------------------------
// Zero pad columns [500,512) of the six f16 P arrays (ws re-poisoned 0xAA).
__global__ __launch_bounds__(256) void padzero_kernel(uint32_t* __restrict__ slab, int R) {
  int idx = blockIdx.x * 256 + threadIdx.x;
  int total = 6 * R * 6;
  if (idx >= total) return;
  int a = idx / (R * 6);
  int rem = idx - a * R * 6;
  int row = rem / 6;
  int q = rem - row * 6;
  slab[(size_t)a * R * 256 + (size_t)row * 256 + 250 + q] = 0u;
}

// ---------------------------------------------------------------------------
// Fused (start-conv) + dilated-conv + gating + GCN channel-mix.
// ROUND 13: each thread handles BOTH n-halves (n0=tid, n1=tid+256): doubles
// per-wave ILP (two independent FMA chains) and halves weight s_loads per
// FMA — probing dcm's persistent 45%-VALUBusy stall. Same arithmetic per
// output in the same order -> bit-identical results.
// h residual stream fp32 (carries A^2-path terms up to ~1e3; f16 failed r8).
// fw/gw are TRANSPOSED [cp][tap][c] weights. All register-array index loops
// fully unrolled (scratch-demotion hazard, r1). Grid: (j, bb).
template <bool FUSED>
__global__ __launch_bounds__(256) void dcm_kernel(
    const float* __restrict__ hprev, const float* __restrict__ xT,
    const float* __restrict__ sw, const float* __restrict__ sb,
    const float* __restrict__ fw, const float* __restrict__ fb,
    const float* __restrict__ gw, const float* __restrict__ gb,
    const float* __restrict__ cw, const float* __restrict__ cb,
    float* __restrict__ Hout,
    f16* __restrict__ P1a,
    f16* __restrict__ P2aH, f16* __restrict__ P2aL,
    f16* __restrict__ P1b,
    f16* __restrict__ P2bH, f16* __restrict__ P2bL,
    float* __restrict__ tapL,
    int Lp, int L, int b0) {
  int j = blockIdx.x, bb = blockIdx.y;
  int n0 = threadIdx.x;
  int n1 = n0 + 256;
  bool ok1 = (n1 < NN);
  int n1c = ok1 ? n1 : n0;  // clamped index for always-valid loads
  size_t base = ((size_t)(bb * 32) * Lp + 2 * j) * NN;
  size_t cs = (size_t)Lp * NN;
  float x00a = 0.f, x01a = 0.f, x10a = 0.f, x11a = 0.f;
  float x00b = 0.f, x01b = 0.f, x10b = 0.f, x11b = 0.f;
  if (FUSED) {
    const float* xb = xT + (size_t)(b0 + bb) * 2 * 256 * NN;
    const float* r0 = xb + (size_t)(2 * j) * NN;
    const float* r1 = xb + (size_t)(2 * j + 1) * NN;
    const float* r2 = xb + (size_t)(256 + 2 * j) * NN;
    const float* r3 = xb + (size_t)(256 + 2 * j + 1) * NN;
    x00a = r0[n0]; x00b = r0[n1c];
    x01a = r1[n0]; x01b = r1[n1c];
    x10a = r2[n0]; x10b = r2[n1c];
    x11a = r3[n0]; x11b = r3[n1c];
  }
  float accf0[32], accg0[32], accf1[32], accg1[32];
#pragma unroll
  for (int c = 0; c < 32; c++) {
    float fbc = fb[c], gbc = gb[c];
    accf0[c] = fbc; accg0[c] = gbc;
    accf1[c] = fbc; accg1[c] = gbc;
  }
#pragma unroll 2
  for (int cp = 0; cp < 32; cp++) {
    float v0a, v1a, v0b, v1b;
    if (FUSED) {
      float w0 = sw[cp * 2], w1 = sw[cp * 2 + 1], bc = sb[cp];
      v0a = fmaf(w0, x00a, fmaf(w1, x10a, bc));
      v1a = fmaf(w0, x01a, fmaf(w1, x11a, bc));
      v0b = fmaf(w0, x00b, fmaf(w1, x10b, bc));
      v1b = fmaf(w0, x01b, fmaf(w1, x11b, bc));
    } else {
      const float* hp = hprev + base + cp * cs;
      v0a = hp[n0];
      v1a = hp[NN + n0];
      v0b = hp[n1c];
      v1b = hp[NN + n1c];
    }
    const float* fwp = fw + cp * 64;  // [cp][tap][c]: 64 contiguous floats
    const float* gwp = gw + cp * 64;
#pragma unroll
    for (int c = 0; c < 32; c++) {
      float fw0 = fwp[c], fw1 = fwp[32 + c];
      float gw0 = gwp[c], gw1 = gwp[32 + c];
      accf0[c] = fmaf(fw0, v0a, accf0[c]);
      accf0[c] = fmaf(fw1, v1a, accf0[c]);
      accg0[c] = fmaf(gw0, v0a, accg0[c]);
      accg0[c] = fmaf(gw1, v1a, accg0[c]);
      accf1[c] = fmaf(fw0, v0b, accf1[c]);
      accf1[c] = fmaf(fw1, v1b, accf1[c]);
      accg1[c] = fmaf(gw0, v0b, accg1[c]);
      accg1[c] = fmaf(gw1, v1b, accg1[c]);
    }
  }
  float FG0[32], FG1[32];
#pragma unroll
  for (int c = 0; c < 32; c++) {
    float E0 = __expf(2.f * accf0[c]);
    float th0 = 1.f - 2.f / (E0 + 1.f);
    float sg0 = 1.f / (1.f + __expf(-accg0[c]));
    FG0[c] = th0 * sg0;
    float E1 = __expf(2.f * accf1[c]);
    float th1 = 1.f - 2.f / (E1 + 1.f);
    float sg1 = 1.f / (1.f + __expf(-accg1[c]));
    FG1[c] = th1 * sg1;
  }
  if (j == L - 1) {
    size_t tbase = ((size_t)(b0 + bb) * 32) * NN;
#pragma unroll
    for (int c = 0; c < 32; c++) {
      tapL[tbase + (size_t)c * NN + n0] = FG0[c];
      if (ok1) tapL[tbase + (size_t)c * NN + n1] = FG1[c];
    }
  }
  if (Hout == nullptr) return;  // layer 8: only the skip tap survives
#pragma unroll 2
  for (int c = 0; c < 32; c++) {
    const float* wr = cw + c * 160;
    float cbc = cb[c];
    float h0 = cbc, p10 = 0.f, p20 = 0.f, q10 = 0.f, q20 = 0.f;
    float h1 = cbc, p11 = 0.f, p21 = 0.f, q11 = 0.f, q21 = 0.f;
#pragma unroll
    for (int cp = 0; cp < 32; cp++) {
      float w0 = wr[cp], w1 = wr[32 + cp], w2 = wr[64 + cp];
      float w3 = wr[96 + cp], w4 = wr[128 + cp];
      float f0 = FG0[cp], f1 = FG1[cp];
      h0  = fmaf(w0, f0, h0);   h1  = fmaf(w0, f1, h1);
      p10 = fmaf(w1, f0, p10);  p11 = fmaf(w1, f1, p11);
      p20 = fmaf(w2, f0, p20);  p21 = fmaf(w2, f1, p21);
      q10 = fmaf(w3, f0, q10);  q11 = fmaf(w3, f1, q11);
      q20 = fmaf(w4, f0, q20);  q21 = fmaf(w4, f1, q21);
    }
    // residual = hprev[2j+1] (start-conv output for layer 0)
    if (FUSED) {
      float sw0 = sw[c * 2], sw1 = sw[c * 2 + 1], sbc = sb[c];
      h0 += fmaf(sw0, x01a, fmaf(sw1, x11a, sbc));
      h1 += fmaf(sw0, x01b, fmaf(sw1, x11b, sbc));
    } else {
      const float* hr = hprev + ((size_t)(bb * 32 + c) * Lp + 2 * j + 1) * NN;
      h0 += hr[n0];
      h1 += hr[n1c];
    }
    size_t mi = (size_t)(bb * 32 + c) * L + j;
    size_t o = mi * KP;
    f16 t;
    Hout[mi * NN + n0] = h0;
    P1a[o + n0] = (f16)p10;
    t = (f16)p20; P2aH[o + n0] = t; P2aL[o + n0] = (f16)(p20 - (float)t);
    P1b[o + n0] = (f16)q10;
    t = (f16)q20; P2bH[o + n0] = t; P2bL[o + n0] = (f16)(q20 - (float)t);
    if (ok1) {
      Hout[mi * NN + n1] = h1;
      P1a[o + n1] = (f16)p11;
      t = (f16)p21; P2aH[o + n1] = t; P2aL[o + n1] = (f16)(p21 - (float)t);
      P1b[o + n1] = (f16)q11;
      t = (f16)q21; P2bH[o + n1] = t; P2bL[o + n1] = (f16)(q21 - (float)t);
    }
  }
}

// ---------------------------------------------------------------------------
// LDS-staged GCN node-mix GEMM (m97-style 2-barrier K-loop + register
// prefetch). Block 128m x 128n, 4 waves of 64x64 (4x4 subtiles of 16x16x32,
// acc=64 VGPR). LDS tiles 128x40 f16 (row pad 32->40: 2-way bank aliasing =
// free). Next 32-k strip prefetched into 16 VGPRs right after the staging
// barrier. Pass loop fully unrolled. Out = BN(Cin + sum_p A_p.B_p), in-place.
__global__ __launch_bounds__(256) void mfma_gcn(PassSet s,
    const float* __restrict__ Cin, float* __restrict__ Out, int M,
    const float* __restrict__ bng, const float* __restrict__ bnb, int lshift) {
  __shared__ f16 As[128 * 40];
  __shared__ f16 Bs[128 * 40];
  int tid = threadIdx.x;
  int wave = tid >> 6, lane = tid & 63;
  int wm = wave >> 1, wn = wave & 1;
  int m0 = blockIdx.x * 128;
  int n0 = blockIdx.y * 128;
  int lm = lane & 15, kq = lane >> 4;  // frag: row lm, k-quad kq (8 k)
  // staging: thread covers rows (tid>>2) and (tid>>2)+64, 16B chunk tid&3
  int srow = tid >> 2, sc = tid & 3;
  int ar0 = m0 + srow;      if (ar0 > M - 1) ar0 = M - 1;
  int ar1 = m0 + srow + 64; if (ar1 > M - 1) ar1 = M - 1;
  size_t ag0 = (size_t)ar0 * KP + sc * 8;
  size_t ag1 = (size_t)ar1 * KP + sc * 8;
  size_t bg0 = (size_t)(n0 + srow) * KP + sc * 8;
  size_t bg1 = (size_t)(n0 + srow + 64) * KP + sc * 8;
  int sl0 = srow * 40 + sc * 8;
  int sl1 = (srow + 64) * 40 + sc * 8;

  floatx4 acc[4][4];
#pragma unroll
  for (int i = 0; i < 4; i++)
#pragma unroll
    for (int j = 0; j < 4; j++) acc[i][j] = (floatx4){0.f, 0.f, 0.f, 0.f};

  float4 pa0, pa1, pb0, pb1;
  {
    const f16* Ap = s.A[0];
    const f16* Bp = s.B[0];
    pa0 = *(const float4*)(Ap + ag0);
    pa1 = *(const float4*)(Ap + ag1);
    pb0 = *(const float4*)(Bp + bg0);
    pb1 = *(const float4*)(Bp + bg1);
  }
#pragma unroll
  for (int p = 0; p < 10; p++) {
    const f16* __restrict__ Ap = s.A[p];
    const f16* __restrict__ Bp = s.B[p];
    const f16* __restrict__ Apn = s.A[p < 9 ? p + 1 : p];
    const f16* __restrict__ Bpn = s.B[p < 9 ? p + 1 : p];
    for (int k0 = 0; k0 < KP; k0 += 32) {
      __syncthreads();  // prior compute done reading LDS
      *(float4*)(As + sl0) = pa0;
      *(float4*)(As + sl1) = pa1;
      *(float4*)(Bs + sl0) = pb0;
      *(float4*)(Bs + sl1) = pb1;
      __syncthreads();  // staging visible
      {  // prefetch next strip; latency overlaps the compute below
        bool lastk = (k0 == KP - 32);
        const f16* An = lastk ? Apn : Ap;
        const f16* Bn = lastk ? Bpn : Bp;
        int kn = lastk ? 0 : k0 + 32;
        pa0 = *(const float4*)(An + ag0 + kn);
        pa1 = *(const float4*)(An + ag1 + kn);
        pb0 = *(const float4*)(Bn + bg0 + kn);
        pb1 = *(const float4*)(Bn + bg1 + kn);
      }
      half8 a[4];
#pragma unroll
      for (int i = 0; i < 4; i++)
        a[i] = *(const half8*)(As + (wm * 64 + i * 16 + lm) * 40 + kq * 8);
#pragma unroll
      for (int j = 0; j < 4; j++) {
        half8 b = *(const half8*)(Bs + (wn * 64 + j * 16 + lm) * 40 + kq * 8);
#pragma unroll
        for (int i = 0; i < 4; i++)
          acc[i][j] = __builtin_amdgcn_mfma_f32_16x16x32_f16(a[i], b, acc[i][j], 0, 0, 0);
      }
    }
  }
  // epilogue: C/D layout col = lane&15, row = (lane>>4)*4 + reg
  int cn = lane & 15, rq = lane >> 4;
  float rs = rsqrtf(1.f + 1e-5f);
#pragma unroll
  for (int i = 0; i < 4; i++) {
#pragma unroll
    for (int r = 0; r < 4; r++) {
      int row = m0 + wm * 64 + i * 16 + rq * 4 + r;
      if (row < M) {
        int c = (row >> lshift) & 31;  // m = (bb*32+c)*L + j
        float scale = bng[c] * rs;
        float bias = bnb[c];
#pragma unroll
        for (int j = 0; j < 4; j++) {
          int col = n0 + wn * 64 + j * 16 + cn;
          if (col < NN) {
            size_t o = (size_t)row * NN + col;
            Out[o] = (acc[i][j][r] + Cin[o]) * scale + bias;
          }
        }
      }
    }
  }
}

// ---------------------------------------------------------------------------
// skip -> relu -> end1 -> relu -> end2. One block per (b, 20 n-values).
#define NB 20
#define NBP 21
__global__ __launch_bounds__(256) void final_kernel(const float* __restrict__ tap,
    const float* __restrict__ skw, const float* __restrict__ skb,
    const float* __restrict__ e1w, const float* __restrict__ e1b,
    const float* __restrict__ e2w, const float* __restrict__ e2b,
    float* __restrict__ out) {
  __shared__ float tapS[256][NBP];
  __shared__ float skS[256][NBP];
  __shared__ float e1S[512][NBP];
  int tid = threadIdx.x;
  int b = blockIdx.y;
  int n0 = blockIdx.x * NB;
  {
    int i = tid >> 5, c = tid & 31;
    const float* tp = tap + (((size_t)i * 8 + b) * 32 + c) * NN + n0;
#pragma unroll
    for (int v = 0; v < NB; v++) tapS[tid][v] = tp[v];
  }
  __syncthreads();
  {
    float bsum = 0.f;
#pragma unroll
    for (int i2 = 0; i2 < 8; i2++) bsum += skb[i2 * 256 + tid];
    float acc[NB];
#pragma unroll
    for (int v = 0; v < NB; v++) acc[v] = bsum;
#pragma unroll
    for (int i2 = 0; i2 < 8; i2++) {
      const float* wr = skw + ((size_t)i2 * 256 + tid) * 32;
#pragma unroll
      for (int cp = 0; cp < 32; cp++) {
        float w = wr[cp];
#pragma unroll
        for (int v = 0; v < NB; v++) acc[v] = fmaf(w, tapS[i2 * 32 + cp][v], acc[v]);
      }
    }
#pragma unroll
    for (int v = 0; v < NB; v++) skS[tid][v] = fmaxf(acc[v], 0.f);
  }
  __syncthreads();
#pragma unroll
  for (int h = 0; h < 2; h++) {
    int k = tid + h * 256;
    float bv = e1b[k];
    float acc[NB];
#pragma unroll
    for (int v = 0; v < NB; v++) acc[v] = bv;
    const float* wr = e1w + (size_t)k * 256;
    for (int o = 0; o < 256; o++) {
      float w = wr[o];
#pragma unroll
      for (int v = 0; v < NB; v++) acc[v] = fmaf(w, skS[o][v], acc[v]);
    }
#pragma unroll
    for (int v = 0; v < NB; v++) e1S[k][v] = fmaxf(acc[v], 0.f);
  }
  __syncthreads();
  if (tid < 12 * NB) {
    int q = tid / NB, v = tid % NB;
    float acc = e2b[q];
    const float* wr = e2w + (size_t)q * 512;
#pragma unroll 8
    for (int k = 0; k < 512; k++) acc = fmaf(wr[k], e1S[k][v], acc);
    out[((size_t)b * 12 + q) * NN + n0 + v] = acc;
  }
}

// ---------------------------------------------------------------------------
extern "C" void kernel_launch(void* const* d_in, const int* in_sizes, int n_in,
                              void* d_out, int out_size, void* d_ws, size_t ws_size,
                              hipStream_t stream) {
  const float* x       = (const float*)d_in[0];
  const float* A0      = (const float*)d_in[1];
  const float* start_w = (const float*)d_in[2];
  const float* start_b = (const float*)d_in[3];
  const float* filt_w  = (const float*)d_in[4];
  const float* filt_b  = (const float*)d_in[5];
  const float* gate_w  = (const float*)d_in[6];
  const float* gate_b  = (const float*)d_in[7];
  const float* skip_w  = (const float*)d_in[8];
  const float* skip_b  = (const float*)d_in[9];
  const float* gcn_w   = (const float*)d_in[10];
  const float* gcn_b   = (const float*)d_in[11];
  const float* bn_g    = (const float*)d_in[12];
  const float* bn_b    = (const float*)d_in[13];
  const float* nv1     = (const float*)d_in[14];
  const float* nv2     = (const float*)d_in[15];
  const float* e1w     = (const float*)d_in[16];
  const float* e1b     = (const float*)d_in[17];
  const float* e2w     = (const float*)d_in[18];
  const float* e2b     = (const float*)d_in[19];
  float* out = (float*)d_out;

  char* ws = (char*)d_ws;
  size_t off = 0;
  auto alloc = [&](size_t bytes) -> void* {
    void* p = (void*)(ws + off);
    off += (bytes + 255) & ~(size_t)255;
    return p;
  };
  float* adp   = (float*)alloc((size_t)NN * NN * 4);
  float* tap   = (float*)alloc((size_t)8 * 8 * 32 * NN * 4);
  float* xT    = (float*)alloc((size_t)16 * 256 * NN * 4);  // [b*2+ch][t][n]
  float* fwT   = (float*)alloc((size_t)16384 * 4);  // dconv weights [i][cp][tap][c]
  float* gwT   = (float*)alloc((size_t)16384 * 4);
  f16*   A0tH  = (f16*)alloc((size_t)KP * KP * 2);
  f16*   A0tL  = (f16*)alloc((size_t)KP * KP * 2);
  f16*   adptH = (f16*)alloc((size_t)KP * KP * 2);
  f16*   adptL = (f16*)alloc((size_t)KP * KP * 2);
  f16*   Q0H   = (f16*)alloc((size_t)KP * KP * 2);   // (A0^2)^T pair
  f16*   Q0L   = (f16*)alloc((size_t)KP * KP * 2);
  f16*   QdH   = (f16*)alloc((size_t)KP * KP * 2);   // (adp^2)^T pair
  f16*   QdL   = (f16*)alloc((size_t)KP * KP * 2);
  size_t fixed = off;

  // Workspace ladder: pick batch-group g and rows-per-batch slab capacity rpb.
  // Layer i (rows/batch = 32*L_i) runs in nCh = ceil(32*L_i/rpb) bb-chunks
  // (pointer offsets only, bit-identical math).
  int g = 1, rpb = 512;
  {
    const int gcand[4] = {8, 4, 2, 1};
    const int rcand[4] = {4096, 2048, 1024, 512};
    bool found = false;
    for (int gi = 0; gi < 4 && !found; gi++) {
      for (int ri = 0; ri < 4 && !found; ri++) {
        int gg = gcand[gi], rr = rcand[ri];
        if (4096 / rr > gg) continue;  // layer-0 chunk count must be <= g
        size_t need = fixed + (size_t)gg * 12288000ull +
                      6ull * gg * rr * KP * 2 + (1u << 20);
        if (need <= ws_size) { g = gg; rpb = rr; found = true; }
      }
    }
  }
  float* h128 = (float*)alloc((size_t)g * 8192000ull);
  float* h64  = (float*)alloc((size_t)g * 4096000ull);
  int R = g * rpb;  // slab rows per f16 array
  f16* slab   = (f16*)alloc(6ull * R * KP * 2);
  f16* P1a  = slab + 0ull * R * KP;
  f16* P2aH = slab + 1ull * R * KP;
  f16* P2aL = slab + 2ull * R * KP;
  f16* P1b  = slab + 3ull * R * KP;
  f16* P2bH = slab + 4ull * R * KP;
  f16* P2bL = slab + 5ull * R * KP;

  adp_kernel<<<NN, 256, 0, stream>>>(nv1, nv2, adp);
  xt_kernel<<<dim3(16, 8, 16), 256, 0, stream>>>(x, xT);
  wtr_kernel<<<64, 256, 0, stream>>>(filt_w, gate_w, fwT, gwT);
  bt_kernel<<<1024, 256, 0, stream>>>(A0, A0tH, A0tL);
  bt_kernel<<<1024, 256, 0, stream>>>(adp, adptH, adptL);
  sq_kernel<<<dim3(512, 2), 512, 0, stream>>>(A0, adp, Q0H, Q0L, QdH, QdL);
  padzero_kernel<<<(36 * R + 255) / 256, 256, 0, stream>>>((uint32_t*)slab, R);

  // out = H + P1a*A0 + P2a*A0^2 + P1b*adp + P2b*adp^2; P2 terms as hi/lo
  // pairs (3 passes, lo*lo dropped), P1 terms single-f16 (2 passes).
  PassSet ps{};
  {
    const f16* Alist[10] = {P1a, P1a, P2aH, P2aH, P2aL, P1b, P1b, P2bH, P2bH, P2bL};
    const f16* Blist[10] = {A0tH, A0tL, Q0H, Q0L, Q0H, adptH, adptL, QdH, QdL, QdH};
    for (int q = 0; q < 10; q++) { ps.A[q] = Alist[q]; ps.B[q] = Blist[q]; }
  }

  for (int b0 = 0; b0 < 8; b0 += g) {
    float* hprev = nullptr;
    int Lp = 256;
    for (int i = 0; i < 8; i++) {
      int L = Lp >> 1;  // 128,64,...,1
      if (i < 7) {
        float* hout = (i & 1) ? h64 : h128;
        int rows = 32 * L;                       // per batch element
        int nCh = (rows + rpb - 1) / rpb;        // bb-chunks (<= g, power of 2)
        if (nCh < 1) nCh = 1;
        int bbw = g / nCh;
        for (int ch = 0; ch < nCh; ch++) {
          int bb0 = ch * bbw;
          const float* hprev_c = hprev ? hprev + (size_t)bb0 * 32 * Lp * NN : nullptr;
          float* hout_c = hout + (size_t)bb0 * 32 * L * NN;
          if (i == 0) {
            dcm_kernel<true><<<dim3(L, bbw), 256, 0, stream>>>(
                nullptr, xT, start_w, start_b,
                fwT + i * 2048, filt_b + i * 32, gwT + i * 2048, gate_b + i * 32,
                gcn_w + i * 5120, gcn_b + i * 32, hout_c,
                P1a, P2aH, P2aL, P1b, P2bH, P2bL,
                tap + (size_t)i * 8 * 32 * NN, Lp, L, b0 + bb0);
          } else {
            dcm_kernel<false><<<dim3(L, bbw), 256, 0, stream>>>(
                hprev_c, nullptr, nullptr, nullptr,
                fwT + i * 2048, filt_b + i * 32, gwT + i * 2048, gate_b + i * 32,
                gcn_w + i * 5120, gcn_b + i * 32, hout_c,
                P1a, P2aH, P2aL, P1b, P2bH, P2bL,
                tap + (size_t)i * 8 * 32 * NN, Lp, L, b0 + bb0);
          }
          int M = bbw * 32 * L;
          int Mb = (M + 127) / 128;
          mfma_gcn<<<dim3(Mb, 4), 256, 0, stream>>>(ps, hout_c, hout_c, M,
                                                    bn_g + i * 32, bn_b + i * 32, 7 - i);
        }
        hprev = hout;
        Lp = L;
      } else {
        // layer 8: only the skip tap survives
        dcm_kernel<false><<<dim3(1, g), 256, 0, stream>>>(
            hprev, nullptr, nullptr, nullptr,
            fwT + i * 2048, filt_b + i * 32, gwT + i * 2048, gate_b + i * 32,
            gcn_w, gcn_b, nullptr,
            P1a, P2aH, P2aL, P1b, P2bH, P2bL,
            tap + (size_t)i * 8 * 32 * NN, Lp, 1, b0);
      }
    }
  }
  final_kernel<<<dim3(25, 8), 256, 0, stream>>>(tap, skip_w, skip_b, e1w, e1b, e2w, e2b, out);
}